// Round 13
// baseline (1598.354 us; speedup 1.0000x reference)
//
#include <hip/hip_runtime.h>
#include <hip/hip_bf16.h>
#include <cstdint>
#include <cstddef>

typedef __attribute__((ext_vector_type(8))) short short8;
typedef __attribute__((ext_vector_type(4))) float f32x4;
typedef __attribute__((ext_vector_type(4))) float f4;
typedef __attribute__((ext_vector_type(4))) short s4;
typedef __attribute__((ext_vector_type(4))) unsigned u32x4;
typedef unsigned short u16;
typedef unsigned long long u64;

#define VOCAB 32000
#define EMB   512
#define HID   1024
#define GDIM  4096   // 4*HID
#define BATCH 16
#define SEQ   256
#define MTOT  4096   // BATCH*SEQ
#define NBLK  64     // lstm blocks

#define SLAB  4096          // bytes per producer slab (1KB data + 3KB pad)
#define BUFB  (NBLK * SLAB) // bytes per h buffer (256 KB)

// head-gemm worker tiling: 32 t-rows x 256 vocab-cols, K=1024
#define TC    32
#define TN    256
#define NT_T  (SEQ / TC)            // 8
#define NT_N  (VOCAB / TN)          // 125
#define NTILES (NT_T * NT_N * BATCH) // 16000

static __device__ __forceinline__ u16 f2bf(float f) {
  unsigned u = __builtin_bit_cast(unsigned, f);
  u += 0x7fffu + ((u >> 16) & 1u);   // RNE
  return (u16)(u >> 16);
}

static __device__ __forceinline__ float fsig(float x) {
  return __builtin_amdgcn_rcpf(1.f + __expf(-x));
}
static __device__ __forceinline__ float ftanh(float x) {
  return 1.f - 2.f * __builtin_amdgcn_rcpf(1.f + __expf(2.f * x));
}

__global__ void cvt_bf16_v4(const float* __restrict__ in, u16* __restrict__ out, long n4) {
  long i = (long)blockIdx.x * blockDim.x + threadIdx.x;
  long stride = (long)gridDim.x * blockDim.x;
  for (; i < n4; i += stride) {
    f4 v = reinterpret_cast<const f4*>(in)[i];
    s4 o;
#pragma unroll
    for (int j = 0; j < 4; ++j) o[j] = (short)f2bf(v[j]);
    reinterpret_cast<s4*>(out)[i] = o;
  }
}

__global__ void embed_gather(const int* __restrict__ x, const float* __restrict__ emb,
                             u16* __restrict__ A) {
  int m = blockIdx.x;                 // m = b*SEQ + t
  long base = (long)x[m] * EMB;
  int e4 = threadIdx.x;               // 0..127, 4 elems each
  f4 v = reinterpret_cast<const f4*>(emb + base)[e4];
  s4 o;
#pragma unroll
  for (int j = 0; j < 4; ++j) o[j] = (short)f2bf(v[j]);
  reinterpret_cast<s4*>(A + (long)m * EMB)[e4] = o;
}

static __device__ __forceinline__ void gload_lds16(const void* g, void* l) {
  __builtin_amdgcn_global_load_lds(
      (const __attribute__((address_space(1))) void*)g,
      (__attribute__((address_space(3))) void*)l, 16, 0, 0);
}

// xg GEMM (r10-validated): C = A*B^T + bias, 128x128 tile, BK=64, swizzled
// staging, bijective XCD grid swizzle. TXG=1: out row = t*BATCH + b.
template<int TXG>
__global__ __launch_bounds__(256) void gemm_bt(
    const u16* __restrict__ A, const u16* __restrict__ B,
    const float* __restrict__ bias, float* __restrict__ C,
    int M, int N, int K)
{
  __shared__ u16 As[128 * 64];
  __shared__ u16 Bs[128 * 64];
  int tid  = threadIdx.x;
  int lane = tid & 63;
  int wid  = tid >> 6;

  int nwg = gridDim.x * gridDim.y;
  int id  = blockIdx.y * gridDim.x + blockIdx.x;
  int id2 = (id & 7) * (nwg >> 3) + (id >> 3);
  int bx  = id2 % gridDim.x, by = id2 / gridDim.x;
  int m0 = by * 128, n0 = bx * 128;

  int wm = (wid >> 1) * 64, wn = (wid & 1) * 64;
  int r  = lane & 15;
  int hi = lane >> 4;
  f32x4 acc[4][4] = {};

  const u16* gaj[4];
  const u16* gbj[4];
  u16* laj[4];
  u16* lbj[4];
#pragma unroll
  for (int j = 0; j < 4; ++j) {
    int c   = wid * 256 + j * 64 + lane;
    int row = c >> 3;
    int gl  = (c & 7) ^ (row & 7);
    gaj[j] = A + (long)(m0 + row) * K + gl * 8;
    gbj[j] = B + (long)(n0 + row) * K + gl * 8;
    laj[j] = As + wid * 2048 + j * 512;
    lbj[j] = Bs + wid * 2048 + j * 512;
  }

  for (int kt = 0; kt < K; kt += 64) {
    __syncthreads();
#pragma unroll
    for (int j = 0; j < 4; ++j) {
      gload_lds16(gaj[j] + kt, laj[j]);
      gload_lds16(gbj[j] + kt, lbj[j]);
    }
    __syncthreads();
    short8 af[2][4], bf[2][4];
#pragma unroll
    for (int ks = 0; ks < 2; ++ks)
#pragma unroll
      for (int i = 0; i < 4; ++i) {
        int ra = wm + i * 16 + r;
        int rb = wn + i * 16 + r;
        af[ks][i] = *reinterpret_cast<const short8*>(
            &As[ra * 64 + ((ks * 4 + hi) ^ (ra & 7)) * 8]);
        bf[ks][i] = *reinterpret_cast<const short8*>(
            &Bs[rb * 64 + ((ks * 4 + hi) ^ (rb & 7)) * 8]);
      }
#pragma unroll
    for (int ks = 0; ks < 2; ++ks)
#pragma unroll
      for (int i = 0; i < 4; ++i)
#pragma unroll
        for (int j = 0; j < 4; ++j)
          acc[i][j] = __builtin_amdgcn_mfma_f32_16x16x32_bf16(
              af[ks][i], bf[ks][j], acc[i][j], 0, 0, 0);
  }

#pragma unroll
  for (int i = 0; i < 4; ++i) {
    int m = m0 + wm + i * 16 + (hi << 2);
#pragma unroll
    for (int j = 0; j < 4; ++j) {
      int n = n0 + wn + j * 16 + r;
      float bv = bias[n];
#pragma unroll
      for (int jj = 0; jj < 4; ++jj) {
        int mm = m + jj;
        long row;
        if constexpr (TXG) {
          row = (long)(mm & (SEQ - 1)) * BATCH + (mm >> 8);  // t*B + b
        } else {
          row = mm;
        }
        C[row * N + n] = acc[i][j][jj] + bv;
      }
    }
  }
}

// FUSED persistent kernel, 256 blocks x 256 threads, PLAIN launch (no
// grid.sync anywhere; co-residency holds structurally: 1 block/CU x 256 CUs,
// LDS 113KB < 160KB). Blocks 0..63: r10 LSTM (tagged h_buf exchange
// verbatim); h_all published via paired-u32 agent atomics. All blocks (lstm
// joins after t-loop) pull head-GEMM tiles from an atomic queue
// (block-uniform fetch via LDS broadcast). Tile A (h_all rows) staged via
// sc1 16B loads with 0xFFFF-sentinel verify-retry (fail-closed); B (head_W)
// via swizzled gload_lds; out = f32 + bias.
__global__ __launch_bounds__(256, 1) void lstm_head_fused(
    const float* __restrict__ xg, const u16* __restrict__ Whh,
    const float* __restrict__ b_hh, unsigned* __restrict__ h_buf,
    u16* __restrict__ h_all, const u16* __restrict__ HW,
    const float* __restrict__ head_b, float* __restrict__ out,
    unsigned* __restrict__ qctr)
{
  __shared__ u16 Alds[32 * 1024];                       // 64 KB
  __shared__ u16 Blds[TN * 64];                         // 32 KB
  __shared__ float part[4][4][16][17];                  // 17.4 KB (lstm only)
  __shared__ unsigned tbase;

  int tid = threadIdx.x;
  int lane = tid & 63, wid = tid >> 6;
  int bid = blockIdx.x;
  int r  = lane & 15;
  int hi = lane >> 4;

  if (bid < NBLK) {
    // ================= LSTM (r10 verbatim + paired h_all publish) ========
    int w = wid;
    int col0 = bid * 16;
    int ko = hi << 3;

    short8 Wf[8][4];
#pragma unroll
    for (int kk8 = 0; kk8 < 8; ++kk8)
#pragma unroll
      for (int g = 0; g < 4; ++g)
        Wf[kk8][g] = *reinterpret_cast<const short8*>(
            Whh + (long)(g * HID + col0 + r) * HID + (w * 256 + kk8 * 32 + ko));

    unsigned soff[2][4];
#pragma unroll
    for (int ph = 0; ph < 2; ++ph)
#pragma unroll
      for (int kk = 0; kk < 4; ++kk) {
        int p = w * 16 + ph * 8 + kk * 2 + (ko >> 4);
        soff[ph][kk] = (unsigned)(p * SLAB + r * 64 + (ko & 8) * 4);
      }
    const char* hbase = reinterpret_cast<const char*>(h_buf);

    int eb = tid >> 4, ec = tid & 15;
    const float* xgp = xg + (long)eb * GDIM + col0 + ec;
    float bias4[4];
#pragma unroll
    for (int g = 0; g < 4; ++g) bias4[g] = b_hh[g * HID + col0 + ec];
    unsigned* h_all32 = reinterpret_cast<unsigned*>(h_all);
    float creg = 0.f;

    __hip_atomic_store(&h_buf[(bid * SLAB / 4) + tid], 1u << 16,
                       __ATOMIC_RELAXED, __HIP_MEMORY_SCOPE_AGENT);

    float xv[4];
#pragma unroll
    for (int g = 0; g < 4; ++g) xv[g] = xgp[g * HID];

    for (int t = 0; t < SEQ; ++t) {
      unsigned want = (unsigned)(t + 1);
      const char* hb = hbase + ((t & 1) ? BUFB : 0);

      f32x4 a0 = {}, a1 = {}, a2 = {}, a3 = {};
#pragma unroll
      for (int ph = 0; ph < 2; ++ph) {
        u32x4 q[4][2];
        for (;;) {
#pragma unroll
          for (int kk = 0; kk < 4; ++kk) {
            const void* a = hb + soff[ph][kk];
            const void* b = hb + soff[ph][kk] + 16;
            asm volatile("global_load_dwordx4 %0, %1, off sc1"
                         : "=v"(q[kk][0]) : "v"(a));
            asm volatile("global_load_dwordx4 %0, %1, off sc1"
                         : "=v"(q[kk][1]) : "v"(b));
          }
          asm volatile("s_waitcnt vmcnt(0)" ::: "memory");
          __builtin_amdgcn_sched_barrier(0);
          bool allok = true;
#pragma unroll
          for (int kk = 0; kk < 4; ++kk)
#pragma unroll
            for (int v = 0; v < 2; ++v)
#pragma unroll
              for (int j = 0; j < 4; ++j)
                allok = allok && ((q[kk][v][j] >> 16) >= want);
          if (__all(allok)) break;
          __builtin_amdgcn_s_sleep(1);
        }

#pragma unroll
        for (int kk = 0; kk < 4; ++kk) {
          u32x4 wv;
          wv[0] = (q[kk][0][0] & 0xffffu) | (q[kk][0][1] << 16);
          wv[1] = (q[kk][0][2] & 0xffffu) | (q[kk][0][3] << 16);
          wv[2] = (q[kk][1][0] & 0xffffu) | (q[kk][1][1] << 16);
          wv[3] = (q[kk][1][2] & 0xffffu) | (q[kk][1][3] << 16);
          short8 av = __builtin_bit_cast(short8, wv);
          a0 = __builtin_amdgcn_mfma_f32_16x16x32_bf16(av, Wf[ph * 4 + kk][0], a0, 0, 0, 0);
          a1 = __builtin_amdgcn_mfma_f32_16x16x32_bf16(av, Wf[ph * 4 + kk][1], a1, 0, 0, 0);
          a2 = __builtin_amdgcn_mfma_f32_16x16x32_bf16(av, Wf[ph * 4 + kk][2], a2, 0, 0, 0);
          a3 = __builtin_amdgcn_mfma_f32_16x16x32_bf16(av, Wf[ph * 4 + kk][3], a3, 0, 0, 0);
        }
      }

#pragma unroll
      for (int j = 0; j < 4; ++j) {
        int batch = (hi << 2) + j;
        part[w][0][batch][r] = a0[j];
        part[w][1][batch][r] = a1[j];
        part[w][2][batch][r] = a2[j];
        part[w][3][batch][r] = a3[j];
      }
      __syncthreads();                       // (A)

      float pre[4];
#pragma unroll
      for (int g = 0; g < 4; ++g)
        pre[g] = part[0][g][eb][ec] + part[1][g][eb][ec] +
                 part[2][g][eb][ec] + part[3][g][eb][ec] + xv[g] + bias4[g];
      float i_ = fsig(pre[0]);
      float f_ = fsig(pre[1]);
      float g_ = ftanh(pre[2]);
      float o_ = fsig(pre[3]);
      float cn = f_ * creg + i_ * g_;
      creg = cn;
      u16 hbf = f2bf(o_ * ftanh(cn));

      // publish h(t+1) to h_buf (critical path)
      if (t + 1 < SEQ) {
        unsigned word = (unsigned)hbf | ((unsigned)(t + 2) << 16);
        __hip_atomic_store(
            &h_buf[(((t + 1) & 1) ? BUFB / 4 : 0) + (bid * SLAB / 4) + tid],
            word, __ATOMIC_RELAXED, __HIP_MEMORY_SCOPE_AGENT);
      }

      // publish h(t) to h_all (paired u32 agent atomic, off critical path)
      {
        unsigned up = (unsigned)__shfl_down((int)(unsigned)hbf, 1);
        if ((ec & 1) == 0) {
          unsigned word = (unsigned)hbf | (up << 16);
          __hip_atomic_store(
              &h_all32[(((size_t)eb * SEQ + t) * HID + col0 + ec) >> 1],
              word, __ATOMIC_RELAXED, __HIP_MEMORY_SCOPE_AGENT);
        }
      }

      int tn = (t + 1 < SEQ) ? t + 1 : t;
#pragma unroll
      for (int g = 0; g < 4; ++g)
        xv[g] = xgp[(long)tn * BATCH * GDIM + g * HID];

      __syncthreads();
    }
  }

  // ================= head-GEMM worker pool (all blocks) ==================
  {
    int brow[8], bgl[8];
    u16* bdst[8];
#pragma unroll
    for (int j = 0; j < 8; ++j) {
      int c = wid * 512 + j * 64 + lane;
      brow[j] = c >> 3;
      bgl[j]  = (c & 7) ^ (brow[j] & 7);
      bdst[j] = Blds + wid * 4096 + j * 512;
    }
    int arow = tid >> 3;                 // A-verify: row 0..31
    int ab   = (tid & 7) * 16;           // starting 16B-chunk within row

    for (;;) {
      __syncthreads();                   // protect tbase + Alds/Blds reuse
      if (tid == 0) tbase = atomicAdd(qctr, 2u);   // BLOCK-uniform fetch
      __syncthreads();
      unsigned T0 = tbase;
      if (T0 >= NTILES) break;
#pragma unroll 1
      for (int s = 0; s < 2; ++s) {
        unsigned T = T0 + s;
        if (T >= NTILES) break;
        int tc = T / (NT_N * BATCH);
        int rem = T % (NT_N * BATCH);
        int nc = rem >> 4, b = rem & 15;

        __syncthreads();                 // protect Alds/Blds from prev tile

        // ---- A: verify (sentinel, fail-closed) + swizzled LDS stage ----
        const char* asrc = reinterpret_cast<const char*>(
            h_all + ((size_t)b * SEQ + tc * TC + arow) * HID) + ab * 16;
#pragma unroll
        for (int g4 = 0; g4 < 4; ++g4) {
          u32x4 d[4];
          for (;;) {
#pragma unroll
            for (int c = 0; c < 4; ++c)
              asm volatile("global_load_dwordx4 %0, %1, off sc1"
                           : "=v"(d[c]) : "v"(asrc + (g4 * 4 + c) * 16));
            asm volatile("s_waitcnt vmcnt(0)" ::: "memory");
            __builtin_amdgcn_sched_barrier(0);
            bool ok = true;
#pragma unroll
            for (int c = 0; c < 4; ++c)
#pragma unroll
              for (int j = 0; j < 4; ++j) {
                unsigned v = d[c][j];
                ok = ok && ((v & 0xffffu) != 0xffffu) && ((v >> 16) != 0xffffu);
              }
            if (ok) break;
            __builtin_amdgcn_s_sleep(8);
          }
#pragma unroll
          for (int c = 0; c < 4; ++c) {
            int c16 = ab + g4 * 4 + c;
            *reinterpret_cast<u32x4*>(
                reinterpret_cast<char*>(Alds) + arow * 2048 +
                (c16 ^ (arow & 7)) * 16) = d[c];
          }
        }
        __syncthreads();

        // ---- K loop ----
        const u16* Bbase = HW + (size_t)(nc * TN) * HID;
        f32x4 acc[2][4] = {};
        for (int kt = 0; kt < 16; ++kt) {
          __syncthreads();
#pragma unroll
          for (int j = 0; j < 8; ++j)
            gload_lds16(Bbase + (size_t)brow[j] * HID + kt * 64 + bgl[j] * 8,
                        bdst[j]);
          __syncthreads();
          short8 af[2][2], bf[2][4];
#pragma unroll
          for (int ks = 0; ks < 2; ++ks) {
#pragma unroll
            for (int mf = 0; mf < 2; ++mf) {
              int ra = mf * 16 + r;
              int c16 = kt * 8 + ks * 4 + hi;
              af[ks][mf] = *reinterpret_cast<const short8*>(
                  reinterpret_cast<const char*>(Alds) + ra * 2048 +
                  (c16 ^ (ra & 7)) * 16);
            }
#pragma unroll
            for (int nf = 0; nf < 4; ++nf) {
              int rb = wid * 64 + nf * 16 + r;
              bf[ks][nf] = *reinterpret_cast<const short8*>(
                  &Blds[rb * 64 + ((ks * 4 + hi) ^ (rb & 7)) * 8]);
            }
          }
#pragma unroll
          for (int ks = 0; ks < 2; ++ks)
#pragma unroll
            for (int mf = 0; mf < 2; ++mf)
#pragma unroll
              for (int nf = 0; nf < 4; ++nf)
                acc[mf][nf] = __builtin_amdgcn_mfma_f32_16x16x32_bf16(
                    af[ks][mf], bf[ks][nf], acc[mf][nf], 0, 0, 0);
        }

        // ---- epilogue ----
        long orow0 = (long)b * SEQ + tc * TC;
#pragma unroll
        for (int mf = 0; mf < 2; ++mf)
#pragma unroll
          for (int nf = 0; nf < 4; ++nf) {
            int n = nc * TN + wid * 64 + nf * 16 + r;
            float bv = head_b[n];
#pragma unroll
            for (int jj = 0; jj < 4; ++jj) {
              int m = mf * 16 + (hi << 2) + jj;
              out[(orow0 + m) * VOCAB + n] = acc[mf][nf][jj] + bv;
            }
          }
      }
    }
  }
}

extern "C" void kernel_launch(void* const* d_in, const int* in_sizes, int n_in,
                              void* d_out, int out_size, void* d_ws, size_t ws_size,
                              hipStream_t stream) {
  const int*   x      = (const int*)d_in[0];
  const float* emb    = (const float*)d_in[1];
  const float* W_ih   = (const float*)d_in[2];
  const float* W_hh   = (const float*)d_in[3];
  const float* b_ih   = (const float*)d_in[4];
  const float* b_hh   = (const float*)d_in[5];
  const float* head_W = (const float*)d_in[6];
  const float* head_b = (const float*)d_in[7];
  float* out = (float*)d_out;

  char* ws = (char*)d_ws;
  size_t off = 0;
  auto alloc = [&](size_t bytes) -> void* {
    void* p = ws + off;
    off += (bytes + 255) & ~(size_t)255;
    return p;
  };
  u16*      Aemb  = (u16*)alloc((size_t)MTOT * EMB * 2);
  u16*      Wih_b = (u16*)alloc((size_t)GDIM * EMB * 2);
  u16*      Whh_b = (u16*)alloc((size_t)GDIM * HID * 2);
  u16*      HW_b  = (u16*)alloc((size_t)VOCAB * HID * 2);
  float*    xg    = (float*)alloc((size_t)MTOT * GDIM * 4);   // time-major [T][B][4H]
  u16*      h_all = (u16*)alloc((size_t)MTOT * HID * 2);
  unsigned* h_buf = (unsigned*)alloc((size_t)2 * BUFB);
  unsigned* qctr  = (unsigned*)alloc(256);

  hipMemsetAsync(h_buf, 0, (size_t)2 * BUFB, stream);          // tags fail closed
  hipMemsetAsync(h_all, 0xFF, (size_t)MTOT * HID * 2, stream); // sentinels
  hipMemsetAsync(qctr, 0, 256, stream);

  cvt_bf16_v4<<<1024, 256, 0, stream>>>(W_ih, Wih_b, (long)GDIM * EMB / 4);
  cvt_bf16_v4<<<1024, 256, 0, stream>>>(W_hh, Whh_b, (long)GDIM * HID / 4);
  cvt_bf16_v4<<<2048, 256, 0, stream>>>(head_W, HW_b, (long)VOCAB * HID / 4);
  embed_gather<<<MTOT, 128, 0, stream>>>(x, emb, Aemb);

  gemm_bt<1><<<dim3(GDIM / 128, MTOT / 128), 256, 0, stream>>>(
      Aemb, Wih_b, b_ih, xg, MTOT, GDIM, EMB);

  // PLAIN launch (r12 used hipLaunchCooperativeKernel at grid=256, which
  // never ran — out stayed zero; no grid.sync inside, so plain is safe)
  lstm_head_fused<<<dim3(256), dim3(256), 0, stream>>>(
      xg, Whh_b, b_hh, h_buf, h_all, HW_b, head_b, out, qctr);
}

// Round 14
// 1583.134 us; speedup vs baseline: 1.0096x; 1.0096x over previous
//
#include <hip/hip_runtime.h>
#include <hip/hip_bf16.h>
#include <cstdint>
#include <cstddef>

typedef __attribute__((ext_vector_type(8))) short short8;
typedef __attribute__((ext_vector_type(4))) float f32x4;
typedef __attribute__((ext_vector_type(4))) float f4;
typedef __attribute__((ext_vector_type(4))) short s4;
typedef __attribute__((ext_vector_type(4))) unsigned u32x4;
typedef unsigned short u16;
typedef unsigned long long u64;

#define VOCAB 32000
#define EMB   512
#define HID   1024
#define GDIM  4096   // 4*HID
#define BATCH 16
#define SEQ   256
#define MTOT  4096   // BATCH*SEQ
#define NBLK  64     // lstm blocks

#define SLAB  4096          // bytes per producer slab (1KB data + 3KB pad)
#define BUFB  (NBLK * SLAB) // bytes per h buffer (256 KB)

// head-gemm worker tiling: 32 t-rows x 256 vocab-cols, K=1024
#define TC    32
#define TN    256
#define NT_T  (SEQ / TC)            // 8
#define NT_N  (VOCAB / TN)          // 125
#define NTILES (NT_T * NT_N * BATCH) // 16000

static __device__ __forceinline__ u16 f2bf(float f) {
  unsigned u = __builtin_bit_cast(unsigned, f);
  u += 0x7fffu + ((u >> 16) & 1u);   // RNE
  return (u16)(u >> 16);
}

static __device__ __forceinline__ float fsig(float x) {
  return __builtin_amdgcn_rcpf(1.f + __expf(-x));
}
static __device__ __forceinline__ float ftanh(float x) {
  return 1.f - 2.f * __builtin_amdgcn_rcpf(1.f + __expf(2.f * x));
}

__global__ void cvt_bf16_v4(const float* __restrict__ in, u16* __restrict__ out, long n4) {
  long i = (long)blockIdx.x * blockDim.x + threadIdx.x;
  long stride = (long)gridDim.x * blockDim.x;
  for (; i < n4; i += stride) {
    f4 v = reinterpret_cast<const f4*>(in)[i];
    s4 o;
#pragma unroll
    for (int j = 0; j < 4; ++j) o[j] = (short)f2bf(v[j]);
    reinterpret_cast<s4*>(out)[i] = o;
  }
}

__global__ void embed_gather(const int* __restrict__ x, const float* __restrict__ emb,
                             u16* __restrict__ A) {
  int m = blockIdx.x;                 // m = b*SEQ + t
  long base = (long)x[m] * EMB;
  int e4 = threadIdx.x;               // 0..127, 4 elems each
  f4 v = reinterpret_cast<const f4*>(emb + base)[e4];
  s4 o;
#pragma unroll
  for (int j = 0; j < 4; ++j) o[j] = (short)f2bf(v[j]);
  reinterpret_cast<s4*>(A + (long)m * EMB)[e4] = o;
}

static __device__ __forceinline__ void gload_lds16(const void* g, void* l) {
  __builtin_amdgcn_global_load_lds(
      (const __attribute__((address_space(1))) void*)g,
      (__attribute__((address_space(3))) void*)l, 16, 0, 0);
}

// xg GEMM (r10-validated): C = A*B^T + bias, 128x128 tile, BK=64, swizzled
// staging, bijective XCD grid swizzle. TXG=1: out row = t*BATCH + b.
template<int TXG>
__global__ __launch_bounds__(256) void gemm_bt(
    const u16* __restrict__ A, const u16* __restrict__ B,
    const float* __restrict__ bias, float* __restrict__ C,
    int M, int N, int K)
{
  __shared__ u16 As[128 * 64];
  __shared__ u16 Bs[128 * 64];
  int tid  = threadIdx.x;
  int lane = tid & 63;
  int wid  = tid >> 6;

  int nwg = gridDim.x * gridDim.y;
  int id  = blockIdx.y * gridDim.x + blockIdx.x;
  int id2 = (id & 7) * (nwg >> 3) + (id >> 3);
  int bx  = id2 % gridDim.x, by = id2 / gridDim.x;
  int m0 = by * 128, n0 = bx * 128;

  int wm = (wid >> 1) * 64, wn = (wid & 1) * 64;
  int r  = lane & 15;
  int hi = lane >> 4;
  f32x4 acc[4][4] = {};

  const u16* gaj[4];
  const u16* gbj[4];
  u16* laj[4];
  u16* lbj[4];
#pragma unroll
  for (int j = 0; j < 4; ++j) {
    int c   = wid * 256 + j * 64 + lane;
    int row = c >> 3;
    int gl  = (c & 7) ^ (row & 7);
    gaj[j] = A + (long)(m0 + row) * K + gl * 8;
    gbj[j] = B + (long)(n0 + row) * K + gl * 8;
    laj[j] = As + wid * 2048 + j * 512;
    lbj[j] = Bs + wid * 2048 + j * 512;
  }

  for (int kt = 0; kt < K; kt += 64) {
    __syncthreads();
#pragma unroll
    for (int j = 0; j < 4; ++j) {
      gload_lds16(gaj[j] + kt, laj[j]);
      gload_lds16(gbj[j] + kt, lbj[j]);
    }
    __syncthreads();
    short8 af[2][4], bf[2][4];
#pragma unroll
    for (int ks = 0; ks < 2; ++ks)
#pragma unroll
      for (int i = 0; i < 4; ++i) {
        int ra = wm + i * 16 + r;
        int rb = wn + i * 16 + r;
        af[ks][i] = *reinterpret_cast<const short8*>(
            &As[ra * 64 + ((ks * 4 + hi) ^ (ra & 7)) * 8]);
        bf[ks][i] = *reinterpret_cast<const short8*>(
            &Bs[rb * 64 + ((ks * 4 + hi) ^ (rb & 7)) * 8]);
      }
#pragma unroll
    for (int ks = 0; ks < 2; ++ks)
#pragma unroll
      for (int i = 0; i < 4; ++i)
#pragma unroll
        for (int j = 0; j < 4; ++j)
          acc[i][j] = __builtin_amdgcn_mfma_f32_16x16x32_bf16(
              af[ks][i], bf[ks][j], acc[i][j], 0, 0, 0);
  }

#pragma unroll
  for (int i = 0; i < 4; ++i) {
    int m = m0 + wm + i * 16 + (hi << 2);
#pragma unroll
    for (int j = 0; j < 4; ++j) {
      int n = n0 + wn + j * 16 + r;
      float bv = bias[n];
#pragma unroll
      for (int jj = 0; jj < 4; ++jj) {
        int mm = m + jj;
        long row;
        if constexpr (TXG) {
          row = (long)(mm & (SEQ - 1)) * BATCH + (mm >> 8);  // t*B + b
        } else {
          row = mm;
        }
        C[row * N + n] = acc[i][j][jj] + bv;
      }
    }
  }
}

// FUSED persistent kernel, 256 blocks x 256 threads, PLAIN launch (no
// grid.sync; co-residency structural: 1 block/CU x 256 CUs). Blocks 0..63:
// r10 LSTM (tagged h_buf exchange verbatim); h_all via paired-u32 agent
// atomics; after each step's end barrier (which drains vmcnt per
// __syncthreads semantics), tid0 fires atomicAdd(done[t]) — the progress
// gate. Workers poll ONE word (done[t_last] == 64) with sleep backoff
// instead of data-polling (r13's sentinel retries congested the coherence
// point and stretched the LSTM 2x). A staged single-shot via sc1 loads +
// swizzled LDS writes; B via swizzled gload_lds; out = f32 + bias.
__global__ __launch_bounds__(256, 1) void lstm_head_fused(
    const float* __restrict__ xg, const u16* __restrict__ Whh,
    const float* __restrict__ b_hh, unsigned* __restrict__ h_buf,
    u16* __restrict__ h_all, const u16* __restrict__ HW,
    const float* __restrict__ head_b, float* __restrict__ out,
    unsigned* __restrict__ qctr, unsigned* __restrict__ done)
{
  __shared__ u16 Alds[32 * 1024];                       // 64 KB
  __shared__ u16 Blds[TN * 64];                         // 32 KB
  __shared__ float part[4][4][16][17];                  // 17.4 KB (lstm only)
  __shared__ unsigned tbase;

  int tid = threadIdx.x;
  int lane = tid & 63, wid = tid >> 6;
  int bid = blockIdx.x;
  int r  = lane & 15;
  int hi = lane >> 4;

  if (bid < NBLK) {
    // ================= LSTM (r10 verbatim + h_all publish + done) ========
    int w = wid;
    int col0 = bid * 16;
    int ko = hi << 3;

    short8 Wf[8][4];
#pragma unroll
    for (int kk8 = 0; kk8 < 8; ++kk8)
#pragma unroll
      for (int g = 0; g < 4; ++g)
        Wf[kk8][g] = *reinterpret_cast<const short8*>(
            Whh + (long)(g * HID + col0 + r) * HID + (w * 256 + kk8 * 32 + ko));

    unsigned soff[2][4];
#pragma unroll
    for (int ph = 0; ph < 2; ++ph)
#pragma unroll
      for (int kk = 0; kk < 4; ++kk) {
        int p = w * 16 + ph * 8 + kk * 2 + (ko >> 4);
        soff[ph][kk] = (unsigned)(p * SLAB + r * 64 + (ko & 8) * 4);
      }
    const char* hbase = reinterpret_cast<const char*>(h_buf);

    int eb = tid >> 4, ec = tid & 15;
    const float* xgp = xg + (long)eb * GDIM + col0 + ec;
    float bias4[4];
#pragma unroll
    for (int g = 0; g < 4; ++g) bias4[g] = b_hh[g * HID + col0 + ec];
    unsigned* h_all32 = reinterpret_cast<unsigned*>(h_all);
    float creg = 0.f;

    __hip_atomic_store(&h_buf[(bid * SLAB / 4) + tid], 1u << 16,
                       __ATOMIC_RELAXED, __HIP_MEMORY_SCOPE_AGENT);

    float xv[4];
#pragma unroll
    for (int g = 0; g < 4; ++g) xv[g] = xgp[g * HID];

    for (int t = 0; t < SEQ; ++t) {
      unsigned want = (unsigned)(t + 1);
      const char* hb = hbase + ((t & 1) ? BUFB : 0);

      f32x4 a0 = {}, a1 = {}, a2 = {}, a3 = {};
#pragma unroll
      for (int ph = 0; ph < 2; ++ph) {
        u32x4 q[4][2];
        for (;;) {
#pragma unroll
          for (int kk = 0; kk < 4; ++kk) {
            const void* a = hb + soff[ph][kk];
            const void* b = hb + soff[ph][kk] + 16;
            asm volatile("global_load_dwordx4 %0, %1, off sc1"
                         : "=v"(q[kk][0]) : "v"(a));
            asm volatile("global_load_dwordx4 %0, %1, off sc1"
                         : "=v"(q[kk][1]) : "v"(b));
          }
          asm volatile("s_waitcnt vmcnt(0)" ::: "memory");
          __builtin_amdgcn_sched_barrier(0);
          bool allok = true;
#pragma unroll
          for (int kk = 0; kk < 4; ++kk)
#pragma unroll
            for (int v = 0; v < 2; ++v)
#pragma unroll
              for (int j = 0; j < 4; ++j)
                allok = allok && ((q[kk][v][j] >> 16) >= want);
          if (__all(allok)) break;
          __builtin_amdgcn_s_sleep(1);
        }

#pragma unroll
        for (int kk = 0; kk < 4; ++kk) {
          u32x4 wv;
          wv[0] = (q[kk][0][0] & 0xffffu) | (q[kk][0][1] << 16);
          wv[1] = (q[kk][0][2] & 0xffffu) | (q[kk][0][3] << 16);
          wv[2] = (q[kk][1][0] & 0xffffu) | (q[kk][1][1] << 16);
          wv[3] = (q[kk][1][2] & 0xffffu) | (q[kk][1][3] << 16);
          short8 av = __builtin_bit_cast(short8, wv);
          a0 = __builtin_amdgcn_mfma_f32_16x16x32_bf16(av, Wf[ph * 4 + kk][0], a0, 0, 0, 0);
          a1 = __builtin_amdgcn_mfma_f32_16x16x32_bf16(av, Wf[ph * 4 + kk][1], a1, 0, 0, 0);
          a2 = __builtin_amdgcn_mfma_f32_16x16x32_bf16(av, Wf[ph * 4 + kk][2], a2, 0, 0, 0);
          a3 = __builtin_amdgcn_mfma_f32_16x16x32_bf16(av, Wf[ph * 4 + kk][3], a3, 0, 0, 0);
        }
      }

#pragma unroll
      for (int j = 0; j < 4; ++j) {
        int batch = (hi << 2) + j;
        part[w][0][batch][r] = a0[j];
        part[w][1][batch][r] = a1[j];
        part[w][2][batch][r] = a2[j];
        part[w][3][batch][r] = a3[j];
      }
      __syncthreads();                       // (A)

      float pre[4];
#pragma unroll
      for (int g = 0; g < 4; ++g)
        pre[g] = part[0][g][eb][ec] + part[1][g][eb][ec] +
                 part[2][g][eb][ec] + part[3][g][eb][ec] + xv[g] + bias4[g];
      float i_ = fsig(pre[0]);
      float f_ = fsig(pre[1]);
      float g_ = ftanh(pre[2]);
      float o_ = fsig(pre[3]);
      float cn = f_ * creg + i_ * g_;
      creg = cn;
      u16 hbf = f2bf(o_ * ftanh(cn));

      // publish h(t+1) to h_buf (critical path)
      if (t + 1 < SEQ) {
        unsigned word = (unsigned)hbf | ((unsigned)(t + 2) << 16);
        __hip_atomic_store(
            &h_buf[(((t + 1) & 1) ? BUFB / 4 : 0) + (bid * SLAB / 4) + tid],
            word, __ATOMIC_RELAXED, __HIP_MEMORY_SCOPE_AGENT);
      }

      // publish h(t) to h_all (paired u32 agent atomic)
      {
        unsigned up = (unsigned)__shfl_down((int)(unsigned)hbf, 1);
        if ((ec & 1) == 0) {
          unsigned word = (unsigned)hbf | (up << 16);
          __hip_atomic_store(
              &h_all32[(((size_t)eb * SEQ + t) * HID + col0 + ec) >> 1],
              word, __ATOMIC_RELAXED, __HIP_MEMORY_SCOPE_AGENT);
        }
      }

      int tn = (t + 1 < SEQ) ? t + 1 : t;
#pragma unroll
      for (int g = 0; g < 4; ++g)
        xv[g] = xgp[(long)tn * BATCH * GDIM + g * HID];

      __syncthreads();   // end-of-step: drains ALL waves' stores (vmcnt 0)
      // progress gate: all this block's h_all(t) stores are now at the
      // coherence point -> safe to announce
      if (tid == 0)
        __hip_atomic_fetch_add(&done[t], 1u, __ATOMIC_RELAXED,
                               __HIP_MEMORY_SCOPE_AGENT);
    }
  }

  // ================= head-GEMM worker pool (all blocks) ==================
  {
    int brow[8], bgl[8];
    u16* bdst[8];
#pragma unroll
    for (int j = 0; j < 8; ++j) {
      int c = wid * 512 + j * 64 + lane;
      brow[j] = c >> 3;
      bgl[j]  = (c & 7) ^ (brow[j] & 7);
      bdst[j] = Blds + wid * 4096 + j * 512;
    }
    int arow = tid >> 3;                 // A-stage: row 0..31
    int ab   = (tid & 7) * 16;           // starting 16B-chunk within row

    for (;;) {
      __syncthreads();                   // protect tbase + Alds/Blds reuse
      if (tid == 0) tbase = atomicAdd(qctr, 2u);   // block-uniform fetch
      __syncthreads();
      unsigned T0 = tbase;
      if (T0 >= NTILES) break;
#pragma unroll 1
      for (int s = 0; s < 2; ++s) {
        unsigned T = T0 + s;
        if (T >= NTILES) break;
        int tc = T / (NT_N * BATCH);
        int rem = T % (NT_N * BATCH);
        int nc = rem >> 4, b = rem & 15;

        // ---- progress gate: ONE word, sleep-backoff (no data polling) ----
        if (tid == 0) {
          int t_last = tc * TC + TC - 1;
          while (__hip_atomic_load(&done[t_last], __ATOMIC_RELAXED,
                                   __HIP_MEMORY_SCOPE_AGENT) < NBLK)
            __builtin_amdgcn_s_sleep(32);
        }
        __syncthreads();                 // gate + protect Alds/Blds

        // ---- A: single-shot sc1 loads + swizzled LDS writes ----
        const char* asrc = reinterpret_cast<const char*>(
            h_all + ((size_t)b * SEQ + tc * TC + arow) * HID) + ab * 16;
#pragma unroll
        for (int g4 = 0; g4 < 4; ++g4) {
          u32x4 d[4];
#pragma unroll
          for (int c = 0; c < 4; ++c)
            asm volatile("global_load_dwordx4 %0, %1, off sc1"
                         : "=v"(d[c]) : "v"(asrc + (g4 * 4 + c) * 16));
          asm volatile("s_waitcnt vmcnt(0)" ::: "memory");
          __builtin_amdgcn_sched_barrier(0);
#pragma unroll
          for (int c = 0; c < 4; ++c) {
            int c16 = ab + g4 * 4 + c;
            *reinterpret_cast<u32x4*>(
                reinterpret_cast<char*>(Alds) + arow * 2048 +
                (c16 ^ (arow & 7)) * 16) = d[c];
          }
        }
        __syncthreads();

        // ---- K loop ----
        const u16* Bbase = HW + (size_t)(nc * TN) * HID;
        f32x4 acc[2][4] = {};
        for (int kt = 0; kt < 16; ++kt) {
          __syncthreads();
#pragma unroll
          for (int j = 0; j < 8; ++j)
            gload_lds16(Bbase + (size_t)brow[j] * HID + kt * 64 + bgl[j] * 8,
                        bdst[j]);
          __syncthreads();
          short8 af[2][2], bf[2][4];
#pragma unroll
          for (int ks = 0; ks < 2; ++ks) {
#pragma unroll
            for (int mf = 0; mf < 2; ++mf) {
              int ra = mf * 16 + r;
              int c16 = kt * 8 + ks * 4 + hi;
              af[ks][mf] = *reinterpret_cast<const short8*>(
                  reinterpret_cast<const char*>(Alds) + ra * 2048 +
                  (c16 ^ (ra & 7)) * 16);
            }
#pragma unroll
            for (int nf = 0; nf < 4; ++nf) {
              int rb = wid * 64 + nf * 16 + r;
              bf[ks][nf] = *reinterpret_cast<const short8*>(
                  &Blds[rb * 64 + ((ks * 4 + hi) ^ (rb & 7)) * 8]);
            }
          }
#pragma unroll
          for (int ks = 0; ks < 2; ++ks)
#pragma unroll
            for (int mf = 0; mf < 2; ++mf)
#pragma unroll
              for (int nf = 0; nf < 4; ++nf)
                acc[mf][nf] = __builtin_amdgcn_mfma_f32_16x16x32_bf16(
                    af[ks][mf], bf[ks][nf], acc[mf][nf], 0, 0, 0);
        }

        // ---- epilogue ----
        long orow0 = (long)b * SEQ + tc * TC;
#pragma unroll
        for (int mf = 0; mf < 2; ++mf)
#pragma unroll
          for (int nf = 0; nf < 4; ++nf) {
            int n = nc * TN + wid * 64 + nf * 16 + r;
            float bv = head_b[n];
#pragma unroll
            for (int jj = 0; jj < 4; ++jj) {
              int m = mf * 16 + (hi << 2) + jj;
              out[(orow0 + m) * VOCAB + n] = acc[mf][nf][jj] + bv;
            }
          }
      }
    }
  }
}

extern "C" void kernel_launch(void* const* d_in, const int* in_sizes, int n_in,
                              void* d_out, int out_size, void* d_ws, size_t ws_size,
                              hipStream_t stream) {
  const int*   x      = (const int*)d_in[0];
  const float* emb    = (const float*)d_in[1];
  const float* W_ih   = (const float*)d_in[2];
  const float* W_hh   = (const float*)d_in[3];
  const float* b_ih   = (const float*)d_in[4];
  const float* b_hh   = (const float*)d_in[5];
  const float* head_W = (const float*)d_in[6];
  const float* head_b = (const float*)d_in[7];
  float* out = (float*)d_out;

  char* ws = (char*)d_ws;
  size_t off = 0;
  auto alloc = [&](size_t bytes) -> void* {
    void* p = ws + off;
    off += (bytes + 255) & ~(size_t)255;
    return p;
  };
  u16*      Aemb  = (u16*)alloc((size_t)MTOT * EMB * 2);
  u16*      Wih_b = (u16*)alloc((size_t)GDIM * EMB * 2);
  u16*      Whh_b = (u16*)alloc((size_t)GDIM * HID * 2);
  u16*      HW_b  = (u16*)alloc((size_t)VOCAB * HID * 2);
  float*    xg    = (float*)alloc((size_t)MTOT * GDIM * 4);   // time-major [T][B][4H]
  u16*      h_all = (u16*)alloc((size_t)MTOT * HID * 2);
  unsigned* h_buf = (unsigned*)alloc((size_t)2 * BUFB);
  unsigned* qctr  = (unsigned*)alloc(256);
  unsigned* done  = (unsigned*)alloc(SEQ * 4);

  hipMemsetAsync(h_buf, 0, (size_t)2 * BUFB, stream);   // tags fail closed
  hipMemsetAsync(qctr, 0, 256, stream);
  hipMemsetAsync(done, 0, SEQ * 4, stream);

  cvt_bf16_v4<<<1024, 256, 0, stream>>>(W_ih, Wih_b, (long)GDIM * EMB / 4);
  cvt_bf16_v4<<<1024, 256, 0, stream>>>(W_hh, Whh_b, (long)GDIM * HID / 4);
  cvt_bf16_v4<<<2048, 256, 0, stream>>>(head_W, HW_b, (long)VOCAB * HID / 4);
  embed_gather<<<MTOT, 128, 0, stream>>>(x, emb, Aemb);

  gemm_bt<1><<<dim3(GDIM / 128, MTOT / 128), 256, 0, stream>>>(
      Aemb, Wih_b, b_ih, xg, MTOT, GDIM, EMB);

  lstm_head_fused<<<dim3(256), dim3(256), 0, stream>>>(
      xg, Whh_b, b_hh, h_buf, h_all, HW_b, head_b, out, qctr, done);
}

// Round 15
// 1535.983 us; speedup vs baseline: 1.0406x; 1.0307x over previous
//
#include <hip/hip_runtime.h>
#include <hip/hip_bf16.h>
#include <cstdint>
#include <cstddef>

typedef __attribute__((ext_vector_type(8))) short short8;
typedef __attribute__((ext_vector_type(4))) float f32x4;
typedef __attribute__((ext_vector_type(4))) float f4;
typedef __attribute__((ext_vector_type(4))) short s4;
typedef __attribute__((ext_vector_type(4))) unsigned u32x4;
typedef unsigned short u16;
typedef unsigned long long u64;

#define VOCAB 32000
#define EMB   512
#define HID   1024
#define GDIM  4096   // 4*HID
#define BATCH 16
#define SEQ   256
#define MTOT  4096   // BATCH*SEQ
#define NBLK  64     // lstm blocks

#define SLAB  4096          // bytes per producer slab (1KB data + 3KB pad)
#define BUFB  (NBLK * SLAB) // bytes per h buffer (256 KB)

// head-gemm worker tiling: 32 t-rows x 256 vocab-cols, K=1024
#define TC    32
#define TN    256
#define NT_T  (SEQ / TC)            // 8
#define NT_N  (VOCAB / TN)          // 125
#define NTILES (NT_T * NT_N * BATCH) // 16000

static __device__ __forceinline__ u16 f2bf(float f) {
  unsigned u = __builtin_bit_cast(unsigned, f);
  u += 0x7fffu + ((u >> 16) & 1u);   // RNE
  return (u16)(u >> 16);
}

static __device__ __forceinline__ float fsig(float x) {
  return __builtin_amdgcn_rcpf(1.f + __expf(-x));
}
static __device__ __forceinline__ float ftanh(float x) {
  return 1.f - 2.f * __builtin_amdgcn_rcpf(1.f + __expf(2.f * x));
}

__global__ void cvt_bf16_v4(const float* __restrict__ in, u16* __restrict__ out, long n4) {
  long i = (long)blockIdx.x * blockDim.x + threadIdx.x;
  long stride = (long)gridDim.x * blockDim.x;
  for (; i < n4; i += stride) {
    f4 v = reinterpret_cast<const f4*>(in)[i];
    s4 o;
#pragma unroll
    for (int j = 0; j < 4; ++j) o[j] = (short)f2bf(v[j]);
    reinterpret_cast<s4*>(out)[i] = o;
  }
}

__global__ void embed_gather(const int* __restrict__ x, const float* __restrict__ emb,
                             u16* __restrict__ A) {
  int m = blockIdx.x;                 // m = b*SEQ + t
  long base = (long)x[m] * EMB;
  int e4 = threadIdx.x;               // 0..127, 4 elems each
  f4 v = reinterpret_cast<const f4*>(emb + base)[e4];
  s4 o;
#pragma unroll
  for (int j = 0; j < 4; ++j) o[j] = (short)f2bf(v[j]);
  reinterpret_cast<s4*>(A + (long)m * EMB)[e4] = o;
}

static __device__ __forceinline__ void gload_lds16(const void* g, void* l) {
  __builtin_amdgcn_global_load_lds(
      (const __attribute__((address_space(1))) void*)g,
      (__attribute__((address_space(3))) void*)l, 16, 0, 0);
}

// xg GEMM (r10-validated): C = A*B^T + bias, 128x128 tile, BK=64, swizzled
// staging, bijective XCD grid swizzle. TXG=1: out row = t*BATCH + b.
template<int TXG>
__global__ __launch_bounds__(256) void gemm_bt(
    const u16* __restrict__ A, const u16* __restrict__ B,
    const float* __restrict__ bias, float* __restrict__ C,
    int M, int N, int K)
{
  __shared__ u16 As[128 * 64];
  __shared__ u16 Bs[128 * 64];
  int tid  = threadIdx.x;
  int lane = tid & 63;
  int wid  = tid >> 6;

  int nwg = gridDim.x * gridDim.y;
  int id  = blockIdx.y * gridDim.x + blockIdx.x;
  int id2 = (id & 7) * (nwg >> 3) + (id >> 3);
  int bx  = id2 % gridDim.x, by = id2 / gridDim.x;
  int m0 = by * 128, n0 = bx * 128;

  int wm = (wid >> 1) * 64, wn = (wid & 1) * 64;
  int r  = lane & 15;
  int hi = lane >> 4;
  f32x4 acc[4][4] = {};

  const u16* gaj[4];
  const u16* gbj[4];
  u16* laj[4];
  u16* lbj[4];
#pragma unroll
  for (int j = 0; j < 4; ++j) {
    int c   = wid * 256 + j * 64 + lane;
    int row = c >> 3;
    int gl  = (c & 7) ^ (row & 7);
    gaj[j] = A + (long)(m0 + row) * K + gl * 8;
    gbj[j] = B + (long)(n0 + row) * K + gl * 8;
    laj[j] = As + wid * 2048 + j * 512;
    lbj[j] = Bs + wid * 2048 + j * 512;
  }

  for (int kt = 0; kt < K; kt += 64) {
    __syncthreads();
#pragma unroll
    for (int j = 0; j < 4; ++j) {
      gload_lds16(gaj[j] + kt, laj[j]);
      gload_lds16(gbj[j] + kt, lbj[j]);
    }
    __syncthreads();
    short8 af[2][4], bf[2][4];
#pragma unroll
    for (int ks = 0; ks < 2; ++ks)
#pragma unroll
      for (int i = 0; i < 4; ++i) {
        int ra = wm + i * 16 + r;
        int rb = wn + i * 16 + r;
        af[ks][i] = *reinterpret_cast<const short8*>(
            &As[ra * 64 + ((ks * 4 + hi) ^ (ra & 7)) * 8]);
        bf[ks][i] = *reinterpret_cast<const short8*>(
            &Bs[rb * 64 + ((ks * 4 + hi) ^ (rb & 7)) * 8]);
      }
#pragma unroll
    for (int ks = 0; ks < 2; ++ks)
#pragma unroll
      for (int i = 0; i < 4; ++i)
#pragma unroll
        for (int j = 0; j < 4; ++j)
          acc[i][j] = __builtin_amdgcn_mfma_f32_16x16x32_bf16(
              af[ks][i], bf[ks][j], acc[i][j], 0, 0, 0);
  }

#pragma unroll
  for (int i = 0; i < 4; ++i) {
    int m = m0 + wm + i * 16 + (hi << 2);
#pragma unroll
    for (int j = 0; j < 4; ++j) {
      int n = n0 + wn + j * 16 + r;
      float bv = bias[n];
#pragma unroll
      for (int jj = 0; jj < 4; ++jj) {
        int mm = m + jj;
        long row;
        if constexpr (TXG) {
          row = (long)(mm & (SEQ - 1)) * BATCH + (mm >> 8);  // t*B + b
        } else {
          row = mm;
        }
        C[row * N + n] = acc[i][j][jj] + bv;
      }
    }
  }
}

// FUSED persistent kernel, 256 blocks x 256 threads, PLAIN launch. Blocks
// 0..63: r10 LSTM (tagged h_buf exchange verbatim); h_all via paired-u32
// agent atomics. Progress gate AMORTIZED: done[tc] announced once per
// 32 steps (at t&31==31, after the end barrier's vmcnt drain) — r14's
// per-step same-line atomicAdd serialized at the coherence point AND its
// ack stalled tid0's next vmcnt(0) tag-poll, stretching every step ~2x.
// Workers poll done[tc]==64 with slow sleep backoff (chunk slack absorbs
// detect latency). A staged single-shot sc1; B via swizzled gload_lds.
__global__ __launch_bounds__(256, 1) void lstm_head_fused(
    const float* __restrict__ xg, const u16* __restrict__ Whh,
    const float* __restrict__ b_hh, unsigned* __restrict__ h_buf,
    u16* __restrict__ h_all, const u16* __restrict__ HW,
    const float* __restrict__ head_b, float* __restrict__ out,
    unsigned* __restrict__ qctr, unsigned* __restrict__ done)
{
  __shared__ u16 Alds[32 * 1024];                       // 64 KB
  __shared__ u16 Blds[TN * 64];                         // 32 KB
  __shared__ float part[4][4][16][17];                  // 17.4 KB (lstm only)
  __shared__ unsigned tbase;

  int tid = threadIdx.x;
  int lane = tid & 63, wid = tid >> 6;
  int bid = blockIdx.x;
  int r  = lane & 15;
  int hi = lane >> 4;

  if (bid < NBLK) {
    // ================= LSTM (r10 verbatim + h_all publish + done) ========
    int w = wid;
    int col0 = bid * 16;
    int ko = hi << 3;

    short8 Wf[8][4];
#pragma unroll
    for (int kk8 = 0; kk8 < 8; ++kk8)
#pragma unroll
      for (int g = 0; g < 4; ++g)
        Wf[kk8][g] = *reinterpret_cast<const short8*>(
            Whh + (long)(g * HID + col0 + r) * HID + (w * 256 + kk8 * 32 + ko));

    unsigned soff[2][4];
#pragma unroll
    for (int ph = 0; ph < 2; ++ph)
#pragma unroll
      for (int kk = 0; kk < 4; ++kk) {
        int p = w * 16 + ph * 8 + kk * 2 + (ko >> 4);
        soff[ph][kk] = (unsigned)(p * SLAB + r * 64 + (ko & 8) * 4);
      }
    const char* hbase = reinterpret_cast<const char*>(h_buf);

    int eb = tid >> 4, ec = tid & 15;
    const float* xgp = xg + (long)eb * GDIM + col0 + ec;
    float bias4[4];
#pragma unroll
    for (int g = 0; g < 4; ++g) bias4[g] = b_hh[g * HID + col0 + ec];
    unsigned* h_all32 = reinterpret_cast<unsigned*>(h_all);
    float creg = 0.f;

    __hip_atomic_store(&h_buf[(bid * SLAB / 4) + tid], 1u << 16,
                       __ATOMIC_RELAXED, __HIP_MEMORY_SCOPE_AGENT);

    float xv[4];
#pragma unroll
    for (int g = 0; g < 4; ++g) xv[g] = xgp[g * HID];

    for (int t = 0; t < SEQ; ++t) {
      unsigned want = (unsigned)(t + 1);
      const char* hb = hbase + ((t & 1) ? BUFB : 0);

      f32x4 a0 = {}, a1 = {}, a2 = {}, a3 = {};
#pragma unroll
      for (int ph = 0; ph < 2; ++ph) {
        u32x4 q[4][2];
        for (;;) {
#pragma unroll
          for (int kk = 0; kk < 4; ++kk) {
            const void* a = hb + soff[ph][kk];
            const void* b = hb + soff[ph][kk] + 16;
            asm volatile("global_load_dwordx4 %0, %1, off sc1"
                         : "=v"(q[kk][0]) : "v"(a));
            asm volatile("global_load_dwordx4 %0, %1, off sc1"
                         : "=v"(q[kk][1]) : "v"(b));
          }
          asm volatile("s_waitcnt vmcnt(0)" ::: "memory");
          __builtin_amdgcn_sched_barrier(0);
          bool allok = true;
#pragma unroll
          for (int kk = 0; kk < 4; ++kk)
#pragma unroll
            for (int v = 0; v < 2; ++v)
#pragma unroll
              for (int j = 0; j < 4; ++j)
                allok = allok && ((q[kk][v][j] >> 16) >= want);
          if (__all(allok)) break;
          __builtin_amdgcn_s_sleep(1);
        }

#pragma unroll
        for (int kk = 0; kk < 4; ++kk) {
          u32x4 wv;
          wv[0] = (q[kk][0][0] & 0xffffu) | (q[kk][0][1] << 16);
          wv[1] = (q[kk][0][2] & 0xffffu) | (q[kk][0][3] << 16);
          wv[2] = (q[kk][1][0] & 0xffffu) | (q[kk][1][1] << 16);
          wv[3] = (q[kk][1][2] & 0xffffu) | (q[kk][1][3] << 16);
          short8 av = __builtin_bit_cast(short8, wv);
          a0 = __builtin_amdgcn_mfma_f32_16x16x32_bf16(av, Wf[ph * 4 + kk][0], a0, 0, 0, 0);
          a1 = __builtin_amdgcn_mfma_f32_16x16x32_bf16(av, Wf[ph * 4 + kk][1], a1, 0, 0, 0);
          a2 = __builtin_amdgcn_mfma_f32_16x16x32_bf16(av, Wf[ph * 4 + kk][2], a2, 0, 0, 0);
          a3 = __builtin_amdgcn_mfma_f32_16x16x32_bf16(av, Wf[ph * 4 + kk][3], a3, 0, 0, 0);
        }
      }

#pragma unroll
      for (int j = 0; j < 4; ++j) {
        int batch = (hi << 2) + j;
        part[w][0][batch][r] = a0[j];
        part[w][1][batch][r] = a1[j];
        part[w][2][batch][r] = a2[j];
        part[w][3][batch][r] = a3[j];
      }
      __syncthreads();                       // (A)

      float pre[4];
#pragma unroll
      for (int g = 0; g < 4; ++g)
        pre[g] = part[0][g][eb][ec] + part[1][g][eb][ec] +
                 part[2][g][eb][ec] + part[3][g][eb][ec] + xv[g] + bias4[g];
      float i_ = fsig(pre[0]);
      float f_ = fsig(pre[1]);
      float g_ = ftanh(pre[2]);
      float o_ = fsig(pre[3]);
      float cn = f_ * creg + i_ * g_;
      creg = cn;
      u16 hbf = f2bf(o_ * ftanh(cn));

      // publish h(t+1) to h_buf (critical path)
      if (t + 1 < SEQ) {
        unsigned word = (unsigned)hbf | ((unsigned)(t + 2) << 16);
        __hip_atomic_store(
            &h_buf[(((t + 1) & 1) ? BUFB / 4 : 0) + (bid * SLAB / 4) + tid],
            word, __ATOMIC_RELAXED, __HIP_MEMORY_SCOPE_AGENT);
      }

      // publish h(t) to h_all (paired u32 agent atomic)
      {
        unsigned up = (unsigned)__shfl_down((int)(unsigned)hbf, 1);
        if ((ec & 1) == 0) {
          unsigned word = (unsigned)hbf | (up << 16);
          __hip_atomic_store(
              &h_all32[(((size_t)eb * SEQ + t) * HID + col0 + ec) >> 1],
              word, __ATOMIC_RELAXED, __HIP_MEMORY_SCOPE_AGENT);
        }
      }

      int tn = (t + 1 < SEQ) ? t + 1 : t;
#pragma unroll
      for (int g = 0; g < 4; ++g)
        xv[g] = xgp[(long)tn * BATCH * GDIM + g * HID];

      __syncthreads();   // end-of-step: drains ALL waves' stores (vmcnt 0)
      // amortized progress gate: announce once per 32-step chunk; the RMW
      // ack stall (~us, serialized across 64 blocks) now amortizes 32x
      if ((t & 31) == 31 && tid == 0)
        __hip_atomic_fetch_add(&done[t >> 5], 1u, __ATOMIC_RELAXED,
                               __HIP_MEMORY_SCOPE_AGENT);
    }
  }

  // ================= head-GEMM worker pool (all blocks) ==================
  {
    int brow[8], bgl[8];
    u16* bdst[8];
#pragma unroll
    for (int j = 0; j < 8; ++j) {
      int c = wid * 512 + j * 64 + lane;
      brow[j] = c >> 3;
      bgl[j]  = (c & 7) ^ (brow[j] & 7);
      bdst[j] = Blds + wid * 4096 + j * 512;
    }
    int arow = tid >> 3;                 // A-stage: row 0..31
    int ab   = (tid & 7) * 16;           // starting 16B-chunk within row

    for (;;) {
      __syncthreads();                   // protect tbase + Alds/Blds reuse
      if (tid == 0) tbase = atomicAdd(qctr, 2u);   // block-uniform fetch
      __syncthreads();
      unsigned T0 = tbase;
      if (T0 >= NTILES) break;
#pragma unroll 1
      for (int s = 0; s < 2; ++s) {
        unsigned T = T0 + s;
        if (T >= NTILES) break;
        int tc = T / (NT_N * BATCH);
        int rem = T % (NT_N * BATCH);
        int nc = rem >> 4, b = rem & 15;

        // ---- chunk gate: ONE word, slow poll (chunk slack >> period) ----
        if (tid == 0) {
          while (__hip_atomic_load(&done[tc], __ATOMIC_RELAXED,
                                   __HIP_MEMORY_SCOPE_AGENT) < NBLK)
            __builtin_amdgcn_s_sleep(200);
        }
        __syncthreads();                 // gate + protect Alds/Blds

        // ---- A: single-shot sc1 loads + swizzled LDS writes ----
        const char* asrc = reinterpret_cast<const char*>(
            h_all + ((size_t)b * SEQ + tc * TC + arow) * HID) + ab * 16;
#pragma unroll
        for (int g4 = 0; g4 < 4; ++g4) {
          u32x4 d[4];
#pragma unroll
          for (int c = 0; c < 4; ++c)
            asm volatile("global_load_dwordx4 %0, %1, off sc1"
                         : "=v"(d[c]) : "v"(asrc + (g4 * 4 + c) * 16));
          asm volatile("s_waitcnt vmcnt(0)" ::: "memory");
          __builtin_amdgcn_sched_barrier(0);
#pragma unroll
          for (int c = 0; c < 4; ++c) {
            int c16 = ab + g4 * 4 + c;
            *reinterpret_cast<u32x4*>(
                reinterpret_cast<char*>(Alds) + arow * 2048 +
                (c16 ^ (arow & 7)) * 16) = d[c];
          }
        }
        __syncthreads();

        // ---- K loop ----
        const u16* Bbase = HW + (size_t)(nc * TN) * HID;
        f32x4 acc[2][4] = {};
        for (int kt = 0; kt < 16; ++kt) {
          __syncthreads();
#pragma unroll
          for (int j = 0; j < 8; ++j)
            gload_lds16(Bbase + (size_t)brow[j] * HID + kt * 64 + bgl[j] * 8,
                        bdst[j]);
          __syncthreads();
          short8 af[2][2], bf[2][4];
#pragma unroll
          for (int ks = 0; ks < 2; ++ks) {
#pragma unroll
            for (int mf = 0; mf < 2; ++mf) {
              int ra = mf * 16 + r;
              int c16 = kt * 8 + ks * 4 + hi;
              af[ks][mf] = *reinterpret_cast<const short8*>(
                  reinterpret_cast<const char*>(Alds) + ra * 2048 +
                  (c16 ^ (ra & 7)) * 16);
            }
#pragma unroll
            for (int nf = 0; nf < 4; ++nf) {
              int rb = wid * 64 + nf * 16 + r;
              bf[ks][nf] = *reinterpret_cast<const short8*>(
                  &Blds[rb * 64 + ((ks * 4 + hi) ^ (rb & 7)) * 8]);
            }
          }
#pragma unroll
          for (int ks = 0; ks < 2; ++ks)
#pragma unroll
            for (int mf = 0; mf < 2; ++mf)
#pragma unroll
              for (int nf = 0; nf < 4; ++nf)
                acc[mf][nf] = __builtin_amdgcn_mfma_f32_16x16x32_bf16(
                    af[ks][mf], bf[ks][nf], acc[mf][nf], 0, 0, 0);
        }

        // ---- epilogue ----
        long orow0 = (long)b * SEQ + tc * TC;
#pragma unroll
        for (int mf = 0; mf < 2; ++mf)
#pragma unroll
          for (int nf = 0; nf < 4; ++nf) {
            int n = nc * TN + wid * 64 + nf * 16 + r;
            float bv = head_b[n];
#pragma unroll
            for (int jj = 0; jj < 4; ++jj) {
              int m = mf * 16 + (hi << 2) + jj;
              out[(orow0 + m) * VOCAB + n] = acc[mf][nf][jj] + bv;
            }
          }
      }
    }
  }
}

extern "C" void kernel_launch(void* const* d_in, const int* in_sizes, int n_in,
                              void* d_out, int out_size, void* d_ws, size_t ws_size,
                              hipStream_t stream) {
  const int*   x      = (const int*)d_in[0];
  const float* emb    = (const float*)d_in[1];
  const float* W_ih   = (const float*)d_in[2];
  const float* W_hh   = (const float*)d_in[3];
  const float* b_ih   = (const float*)d_in[4];
  const float* b_hh   = (const float*)d_in[5];
  const float* head_W = (const float*)d_in[6];
  const float* head_b = (const float*)d_in[7];
  float* out = (float*)d_out;

  char* ws = (char*)d_ws;
  size_t off = 0;
  auto alloc = [&](size_t bytes) -> void* {
    void* p = ws + off;
    off += (bytes + 255) & ~(size_t)255;
    return p;
  };
  u16*      Aemb  = (u16*)alloc((size_t)MTOT * EMB * 2);
  u16*      Wih_b = (u16*)alloc((size_t)GDIM * EMB * 2);
  u16*      Whh_b = (u16*)alloc((size_t)GDIM * HID * 2);
  u16*      HW_b  = (u16*)alloc((size_t)VOCAB * HID * 2);
  float*    xg    = (float*)alloc((size_t)MTOT * GDIM * 4);   // time-major [T][B][4H]
  u16*      h_all = (u16*)alloc((size_t)MTOT * HID * 2);
  unsigned* h_buf = (unsigned*)alloc((size_t)2 * BUFB);
  unsigned* qctr  = (unsigned*)alloc(256);
  unsigned* done  = (unsigned*)alloc(256);

  hipMemsetAsync(h_buf, 0, (size_t)2 * BUFB, stream);   // tags fail closed
  hipMemsetAsync(qctr, 0, 256, stream);
  hipMemsetAsync(done, 0, 256, stream);

  cvt_bf16_v4<<<1024, 256, 0, stream>>>(W_ih, Wih_b, (long)GDIM * EMB / 4);
  cvt_bf16_v4<<<1024, 256, 0, stream>>>(W_hh, Whh_b, (long)GDIM * HID / 4);
  cvt_bf16_v4<<<2048, 256, 0, stream>>>(head_W, HW_b, (long)VOCAB * HID / 4);
  embed_gather<<<MTOT, 128, 0, stream>>>(x, emb, Aemb);

  gemm_bt<1><<<dim3(GDIM / 128, MTOT / 128), 256, 0, stream>>>(
      Aemb, Wih_b, b_ih, xg, MTOT, GDIM, EMB);

  lstm_head_fused<<<dim3(256), dim3(256), 0, stream>>>(
      xg, Whh_b, b_hh, h_buf, h_all, HW_b, head_b, out, qctr, done);
}

// Round 16
// 1314.542 us; speedup vs baseline: 1.2159x; 1.1685x over previous
//
#include <hip/hip_runtime.h>
#include <hip/hip_bf16.h>
#include <cstdint>
#include <cstddef>

typedef __attribute__((ext_vector_type(8))) short short8;
typedef __attribute__((ext_vector_type(4))) float f32x4;
typedef __attribute__((ext_vector_type(4))) float f4;
typedef __attribute__((ext_vector_type(4))) short s4;
typedef __attribute__((ext_vector_type(4))) unsigned u32x4;
typedef unsigned short u16;
typedef unsigned long long u64;

#define VOCAB 32000
#define EMB   512
#define HID   1024
#define GDIM  4096   // 4*HID
#define BATCH 16
#define SEQ   256
#define MTOT  4096   // BATCH*SEQ
#define NBLK  64     // lstm blocks

#define SLAB  4096          // bytes per producer slab (1KB data + 3KB pad)
#define BUFB  (NBLK * SLAB) // bytes per h buffer (256 KB)

// head-gemm worker tiling: 128x128, half-major t order
#define NTILE2     8000              // (4096/128) * (32000/128)
#define TPH        4000              // tiles per t-half

static __device__ __forceinline__ u16 f2bf(float f) {
  unsigned u = __builtin_bit_cast(unsigned, f);
  u += 0x7fffu + ((u >> 16) & 1u);   // RNE
  return (u16)(u >> 16);
}

static __device__ __forceinline__ float fsig(float x) {
  return __builtin_amdgcn_rcpf(1.f + __expf(-x));
}
static __device__ __forceinline__ float ftanh(float x) {
  return 1.f - 2.f * __builtin_amdgcn_rcpf(1.f + __expf(2.f * x));
}

__global__ void cvt_bf16_v4(const float* __restrict__ in, u16* __restrict__ out, long n4) {
  long i = (long)blockIdx.x * blockDim.x + threadIdx.x;
  long stride = (long)gridDim.x * blockDim.x;
  for (; i < n4; i += stride) {
    f4 v = reinterpret_cast<const f4*>(in)[i];
    s4 o;
#pragma unroll
    for (int j = 0; j < 4; ++j) o[j] = (short)f2bf(v[j]);
    reinterpret_cast<s4*>(out)[i] = o;
  }
}

__global__ void embed_gather(const int* __restrict__ x, const float* __restrict__ emb,
                             u16* __restrict__ A) {
  int m = blockIdx.x;                 // m = b*SEQ + t
  long base = (long)x[m] * EMB;
  int e4 = threadIdx.x;               // 0..127, 4 elems each
  f4 v = reinterpret_cast<const f4*>(emb + base)[e4];
  s4 o;
#pragma unroll
  for (int j = 0; j < 4; ++j) o[j] = (short)f2bf(v[j]);
  reinterpret_cast<s4*>(A + (long)m * EMB)[e4] = o;
}

static __device__ __forceinline__ void gload_lds16(const void* g, void* l) {
  __builtin_amdgcn_global_load_lds(
      (const __attribute__((address_space(1))) void*)g,
      (__attribute__((address_space(3))) void*)l, 16, 0, 0);
}

// xg GEMM (r10-validated): C = A*B^T + bias, 128x128 tile, BK=64, swizzled
// staging, bijective XCD grid swizzle. TXG=1: out row = t*BATCH + b.
template<int TXG>
__global__ __launch_bounds__(256) void gemm_bt(
    const u16* __restrict__ A, const u16* __restrict__ B,
    const float* __restrict__ bias, float* __restrict__ C,
    int M, int N, int K)
{
  __shared__ u16 As[128 * 64];
  __shared__ u16 Bs[128 * 64];
  int tid  = threadIdx.x;
  int lane = tid & 63;
  int wid  = tid >> 6;

  int nwg = gridDim.x * gridDim.y;
  int id  = blockIdx.y * gridDim.x + blockIdx.x;
  int id2 = (id & 7) * (nwg >> 3) + (id >> 3);
  int bx  = id2 % gridDim.x, by = id2 / gridDim.x;
  int m0 = by * 128, n0 = bx * 128;

  int wm = (wid >> 1) * 64, wn = (wid & 1) * 64;
  int r  = lane & 15;
  int hi = lane >> 4;
  f32x4 acc[4][4] = {};

  const u16* gaj[4];
  const u16* gbj[4];
  u16* laj[4];
  u16* lbj[4];
#pragma unroll
  for (int j = 0; j < 4; ++j) {
    int c   = wid * 256 + j * 64 + lane;
    int row = c >> 3;
    int gl  = (c & 7) ^ (row & 7);
    gaj[j] = A + (long)(m0 + row) * K + gl * 8;
    gbj[j] = B + (long)(n0 + row) * K + gl * 8;
    laj[j] = As + wid * 2048 + j * 512;
    lbj[j] = Bs + wid * 2048 + j * 512;
  }

  for (int kt = 0; kt < K; kt += 64) {
    __syncthreads();
#pragma unroll
    for (int j = 0; j < 4; ++j) {
      gload_lds16(gaj[j] + kt, laj[j]);
      gload_lds16(gbj[j] + kt, lbj[j]);
    }
    __syncthreads();
    short8 af[2][4], bf[2][4];
#pragma unroll
    for (int ks = 0; ks < 2; ++ks)
#pragma unroll
      for (int i = 0; i < 4; ++i) {
        int ra = wm + i * 16 + r;
        int rb = wn + i * 16 + r;
        af[ks][i] = *reinterpret_cast<const short8*>(
            &As[ra * 64 + ((ks * 4 + hi) ^ (ra & 7)) * 8]);
        bf[ks][i] = *reinterpret_cast<const short8*>(
            &Bs[rb * 64 + ((ks * 4 + hi) ^ (rb & 7)) * 8]);
      }
#pragma unroll
    for (int ks = 0; ks < 2; ++ks)
#pragma unroll
      for (int i = 0; i < 4; ++i)
#pragma unroll
        for (int j = 0; j < 4; ++j)
          acc[i][j] = __builtin_amdgcn_mfma_f32_16x16x32_bf16(
              af[ks][i], bf[ks][j], acc[i][j], 0, 0, 0);
  }

#pragma unroll
  for (int i = 0; i < 4; ++i) {
    int m = m0 + wm + i * 16 + (hi << 2);
#pragma unroll
    for (int j = 0; j < 4; ++j) {
      int n = n0 + wn + j * 16 + r;
      float bv = bias[n];
#pragma unroll
      for (int jj = 0; jj < 4; ++jj) {
        int mm = m + jj;
        long row;
        if constexpr (TXG) {
          row = (long)(mm & (SEQ - 1)) * BATCH + (mm >> 8);  // t*B + b
        } else {
          row = mm;
        }
        C[row * N + n] = acc[i][j][jj] + bv;
      }
    }
  }
}

// FUSED persistent kernel, 256 blocks x 256 threads, PLAIN launch. Blocks
// 0..63: r10 LSTM verbatim + amortized done[tc] gate (once per 32 steps).
// Workers: 128x128 head-GEMM tiles (r10 gemm_bt structure — 2x MFMA/barrier,
// 2.3x less L2/L3 streaming than the r13-15 TC=32 worker), half-major t
// order gated on done[3]/done[7] only. A staged per-kt via sc1 loads +
// swizzled ds_write (gate certifies visibility); B via swizzled gload_lds.
__global__ __launch_bounds__(256, 1) void lstm_head_fused(
    const float* __restrict__ xg, const u16* __restrict__ Whh,
    const float* __restrict__ b_hh, unsigned* __restrict__ h_buf,
    u16* __restrict__ h_all, const u16* __restrict__ HW,
    const float* __restrict__ head_b, float* __restrict__ out,
    unsigned* __restrict__ qctr, unsigned* __restrict__ done)
{
  __shared__ u16 Alds[128 * 64];                        // 16 KB
  __shared__ u16 Blds[128 * 64];                        // 16 KB
  __shared__ float part[4][4][16][17];                  // 17.4 KB (lstm only)
  __shared__ unsigned tbase;

  int tid = threadIdx.x;
  int lane = tid & 63, wid = tid >> 6;
  int bid = blockIdx.x;
  int r  = lane & 15;
  int hi = lane >> 4;

  if (bid < NBLK) {
    // ================= LSTM (r15 verbatim) ==============================
    int w = wid;
    int col0 = bid * 16;
    int ko = hi << 3;

    short8 Wf[8][4];
#pragma unroll
    for (int kk8 = 0; kk8 < 8; ++kk8)
#pragma unroll
      for (int g = 0; g < 4; ++g)
        Wf[kk8][g] = *reinterpret_cast<const short8*>(
            Whh + (long)(g * HID + col0 + r) * HID + (w * 256 + kk8 * 32 + ko));

    unsigned soff[2][4];
#pragma unroll
    for (int ph = 0; ph < 2; ++ph)
#pragma unroll
      for (int kk = 0; kk < 4; ++kk) {
        int p = w * 16 + ph * 8 + kk * 2 + (ko >> 4);
        soff[ph][kk] = (unsigned)(p * SLAB + r * 64 + (ko & 8) * 4);
      }
    const char* hbase = reinterpret_cast<const char*>(h_buf);

    int eb = tid >> 4, ec = tid & 15;
    const float* xgp = xg + (long)eb * GDIM + col0 + ec;
    float bias4[4];
#pragma unroll
    for (int g = 0; g < 4; ++g) bias4[g] = b_hh[g * HID + col0 + ec];
    unsigned* h_all32 = reinterpret_cast<unsigned*>(h_all);
    float creg = 0.f;

    __hip_atomic_store(&h_buf[(bid * SLAB / 4) + tid], 1u << 16,
                       __ATOMIC_RELAXED, __HIP_MEMORY_SCOPE_AGENT);

    float xv[4];
#pragma unroll
    for (int g = 0; g < 4; ++g) xv[g] = xgp[g * HID];

    for (int t = 0; t < SEQ; ++t) {
      unsigned want = (unsigned)(t + 1);
      const char* hb = hbase + ((t & 1) ? BUFB : 0);

      f32x4 a0 = {}, a1 = {}, a2 = {}, a3 = {};
#pragma unroll
      for (int ph = 0; ph < 2; ++ph) {
        u32x4 q[4][2];
        for (;;) {
#pragma unroll
          for (int kk = 0; kk < 4; ++kk) {
            const void* a = hb + soff[ph][kk];
            const void* b = hb + soff[ph][kk] + 16;
            asm volatile("global_load_dwordx4 %0, %1, off sc1"
                         : "=v"(q[kk][0]) : "v"(a));
            asm volatile("global_load_dwordx4 %0, %1, off sc1"
                         : "=v"(q[kk][1]) : "v"(b));
          }
          asm volatile("s_waitcnt vmcnt(0)" ::: "memory");
          __builtin_amdgcn_sched_barrier(0);
          bool allok = true;
#pragma unroll
          for (int kk = 0; kk < 4; ++kk)
#pragma unroll
            for (int v = 0; v < 2; ++v)
#pragma unroll
              for (int j = 0; j < 4; ++j)
                allok = allok && ((q[kk][v][j] >> 16) >= want);
          if (__all(allok)) break;
          __builtin_amdgcn_s_sleep(1);
        }

#pragma unroll
        for (int kk = 0; kk < 4; ++kk) {
          u32x4 wv;
          wv[0] = (q[kk][0][0] & 0xffffu) | (q[kk][0][1] << 16);
          wv[1] = (q[kk][0][2] & 0xffffu) | (q[kk][0][3] << 16);
          wv[2] = (q[kk][1][0] & 0xffffu) | (q[kk][1][1] << 16);
          wv[3] = (q[kk][1][2] & 0xffffu) | (q[kk][1][3] << 16);
          short8 av = __builtin_bit_cast(short8, wv);
          a0 = __builtin_amdgcn_mfma_f32_16x16x32_bf16(av, Wf[ph * 4 + kk][0], a0, 0, 0, 0);
          a1 = __builtin_amdgcn_mfma_f32_16x16x32_bf16(av, Wf[ph * 4 + kk][1], a1, 0, 0, 0);
          a2 = __builtin_amdgcn_mfma_f32_16x16x32_bf16(av, Wf[ph * 4 + kk][2], a2, 0, 0, 0);
          a3 = __builtin_amdgcn_mfma_f32_16x16x32_bf16(av, Wf[ph * 4 + kk][3], a3, 0, 0, 0);
        }
      }

#pragma unroll
      for (int j = 0; j < 4; ++j) {
        int batch = (hi << 2) + j;
        part[w][0][batch][r] = a0[j];
        part[w][1][batch][r] = a1[j];
        part[w][2][batch][r] = a2[j];
        part[w][3][batch][r] = a3[j];
      }
      __syncthreads();                       // (A)

      float pre[4];
#pragma unroll
      for (int g = 0; g < 4; ++g)
        pre[g] = part[0][g][eb][ec] + part[1][g][eb][ec] +
                 part[2][g][eb][ec] + part[3][g][eb][ec] + xv[g] + bias4[g];
      float i_ = fsig(pre[0]);
      float f_ = fsig(pre[1]);
      float g_ = ftanh(pre[2]);
      float o_ = fsig(pre[3]);
      float cn = f_ * creg + i_ * g_;
      creg = cn;
      u16 hbf = f2bf(o_ * ftanh(cn));

      if (t + 1 < SEQ) {
        unsigned word = (unsigned)hbf | ((unsigned)(t + 2) << 16);
        __hip_atomic_store(
            &h_buf[(((t + 1) & 1) ? BUFB / 4 : 0) + (bid * SLAB / 4) + tid],
            word, __ATOMIC_RELAXED, __HIP_MEMORY_SCOPE_AGENT);
      }

      {
        unsigned up = (unsigned)__shfl_down((int)(unsigned)hbf, 1);
        if ((ec & 1) == 0) {
          unsigned word = (unsigned)hbf | (up << 16);
          __hip_atomic_store(
              &h_all32[(((size_t)eb * SEQ + t) * HID + col0 + ec) >> 1],
              word, __ATOMIC_RELAXED, __HIP_MEMORY_SCOPE_AGENT);
        }
      }

      int tn = (t + 1 < SEQ) ? t + 1 : t;
#pragma unroll
      for (int g = 0; g < 4; ++g)
        xv[g] = xgp[(long)tn * BATCH * GDIM + g * HID];

      __syncthreads();   // end-of-step: drains ALL waves' stores (vmcnt 0)
      if ((t & 31) == 31 && tid == 0)
        __hip_atomic_fetch_add(&done[t >> 5], 1u, __ATOMIC_RELAXED,
                               __HIP_MEMORY_SCOPE_AGENT);
    }
  }

  // ================= head-GEMM worker pool (all blocks) ==================
  {
    int wm = (wid >> 1) * 64, wn = (wid & 1) * 64;
    // staging pattern (chunk c -> row, group), shared by A and B paths
    int srow[4], sgl[4], sch[4];
    u16* lbj[4];
#pragma unroll
    for (int j = 0; j < 4; ++j) {
      int c = wid * 256 + j * 64 + lane;
      srow[j] = c >> 3;
      sch[j]  = c & 7;
      sgl[j]  = (c & 7) ^ (srow[j] & 7);
      lbj[j]  = Blds + wid * 2048 + j * 512;
    }

    for (;;) {
      __syncthreads();                   // protect tbase + LDS reuse
      if (tid == 0) tbase = atomicAdd(qctr, 1u);   // block-uniform fetch
      __syncthreads();
      unsigned T = tbase;
      if (T >= NTILE2) break;

      int half = (int)(T / TPH);         // 0: t<128, 1: t>=128
      int rem  = (int)(T % TPH);
      int nc   = rem / BATCH;            // 0..249
      int b    = rem % BATCH;
      int m0 = b * SEQ + half * 128;
      int n0 = nc * 128;

      // ---- chunk gate: ONE word per half, slow poll ----
      if (tid == 0) {
        while (__hip_atomic_load(&done[half * 4 + 3], __ATOMIC_RELAXED,
                                 __HIP_MEMORY_SCOPE_AGENT) < NBLK)
          __builtin_amdgcn_s_sleep(200);
      }
      __syncthreads();                   // gate + protect LDS

      const char* Abase = reinterpret_cast<const char*>(h_all) + (size_t)m0 * 2048;
      const u16* Bbase = HW + (size_t)n0 * HID;

      f32x4 acc[4][4] = {};
      for (int kt = 0; kt < HID; kt += 64) {
        __syncthreads();                 // prev kt LDS reads done
        // A: sc1 loads (coherent-fresh h_all) -> swizzled ds_write
        u32x4 av4[4];
#pragma unroll
        for (int j = 0; j < 4; ++j) {
          const void* src = Abase + (size_t)srow[j] * 2048 + (size_t)kt * 2 + sch[j] * 16;
          asm volatile("global_load_dwordx4 %0, %1, off sc1"
                       : "=v"(av4[j]) : "v"(src));
        }
        asm volatile("s_waitcnt vmcnt(0)" ::: "memory");
        __builtin_amdgcn_sched_barrier(0);
#pragma unroll
        for (int j = 0; j < 4; ++j)
          *reinterpret_cast<u32x4*>(
              reinterpret_cast<char*>(Alds) + srow[j] * 128 + sgl[j] * 16) = av4[j];
        // B: swizzled-source gload_lds
#pragma unroll
        for (int j = 0; j < 4; ++j)
          gload_lds16(Bbase + (size_t)srow[j] * HID + kt + sgl[j] * 8, lbj[j]);
        __syncthreads();                 // staging complete

        short8 af[2][4], bf[2][4];
#pragma unroll
        for (int ks = 0; ks < 2; ++ks)
#pragma unroll
          for (int i = 0; i < 4; ++i) {
            int ra = wm + i * 16 + r;
            int rb = wn + i * 16 + r;
            af[ks][i] = *reinterpret_cast<const short8*>(
                &Alds[ra * 64 + ((ks * 4 + hi) ^ (ra & 7)) * 8]);
            bf[ks][i] = *reinterpret_cast<const short8*>(
                &Blds[rb * 64 + ((ks * 4 + hi) ^ (rb & 7)) * 8]);
          }
#pragma unroll
        for (int ks = 0; ks < 2; ++ks)
#pragma unroll
          for (int i = 0; i < 4; ++i)
#pragma unroll
            for (int j = 0; j < 4; ++j)
              acc[i][j] = __builtin_amdgcn_mfma_f32_16x16x32_bf16(
                  af[ks][i], bf[ks][j], acc[i][j], 0, 0, 0);
      }

      // ---- epilogue ----
#pragma unroll
      for (int i = 0; i < 4; ++i) {
        int m = m0 + wm + i * 16 + (hi << 2);
#pragma unroll
        for (int j = 0; j < 4; ++j) {
          int n = n0 + wn + j * 16 + r;
          float bv = head_b[n];
#pragma unroll
          for (int jj = 0; jj < 4; ++jj)
            out[(long)(m + jj) * VOCAB + n] = acc[i][j][jj] + bv;
        }
      }
    }
  }
}

extern "C" void kernel_launch(void* const* d_in, const int* in_sizes, int n_in,
                              void* d_out, int out_size, void* d_ws, size_t ws_size,
                              hipStream_t stream) {
  const int*   x      = (const int*)d_in[0];
  const float* emb    = (const float*)d_in[1];
  const float* W_ih   = (const float*)d_in[2];
  const float* W_hh   = (const float*)d_in[3];
  const float* b_ih   = (const float*)d_in[4];
  const float* b_hh   = (const float*)d_in[5];
  const float* head_W = (const float*)d_in[6];
  const float* head_b = (const float*)d_in[7];
  float* out = (float*)d_out;

  char* ws = (char*)d_ws;
  size_t off = 0;
  auto alloc = [&](size_t bytes) -> void* {
    void* p = ws + off;
    off += (bytes + 255) & ~(size_t)255;
    return p;
  };
  u16*      Aemb  = (u16*)alloc((size_t)MTOT * EMB * 2);
  u16*      Wih_b = (u16*)alloc((size_t)GDIM * EMB * 2);
  u16*      Whh_b = (u16*)alloc((size_t)GDIM * HID * 2);
  u16*      HW_b  = (u16*)alloc((size_t)VOCAB * HID * 2);
  float*    xg    = (float*)alloc((size_t)MTOT * GDIM * 4);   // time-major [T][B][4H]
  u16*      h_all = (u16*)alloc((size_t)MTOT * HID * 2);
  unsigned* h_buf = (unsigned*)alloc((size_t)2 * BUFB);
  unsigned* qctr  = (unsigned*)alloc(256);
  unsigned* done  = (unsigned*)alloc(256);

  hipMemsetAsync(h_buf, 0, (size_t)2 * BUFB, stream);   // tags fail closed
  hipMemsetAsync(qctr, 0, 256, stream);
  hipMemsetAsync(done, 0, 256, stream);

  cvt_bf16_v4<<<1024, 256, 0, stream>>>(W_ih, Wih_b, (long)GDIM * EMB / 4);
  cvt_bf16_v4<<<1024, 256, 0, stream>>>(W_hh, Whh_b, (long)GDIM * HID / 4);
  cvt_bf16_v4<<<2048, 256, 0, stream>>>(head_W, HW_b, (long)VOCAB * HID / 4);
  embed_gather<<<MTOT, 128, 0, stream>>>(x, emb, Aemb);

  gemm_bt<1><<<dim3(GDIM / 128, MTOT / 128), 256, 0, stream>>>(
      Aemb, Wih_b, b_ih, xg, MTOT, GDIM, EMB);

  lstm_head_fused<<<dim3(256), dim3(256), 0, stream>>>(
      xg, Whh_b, b_hh, h_buf, h_all, HW_b, head_b, out, qctr, done);
}

// Round 17
// 1145.869 us; speedup vs baseline: 1.3949x; 1.1472x over previous
//
#include <hip/hip_runtime.h>
#include <hip/hip_bf16.h>
#include <cstdint>
#include <cstddef>

typedef __attribute__((ext_vector_type(8))) short short8;
typedef __attribute__((ext_vector_type(4))) float f32x4;
typedef __attribute__((ext_vector_type(4))) float f4;
typedef __attribute__((ext_vector_type(4))) short s4;
typedef __attribute__((ext_vector_type(4))) unsigned u32x4;
typedef unsigned short u16;
typedef unsigned long long u64;

#define VOCAB 32000
#define EMB   512
#define HID   1024
#define GDIM  4096   // 4*HID
#define BATCH 16
#define SEQ   256
#define MTOT  4096   // BATCH*SEQ
#define NBLK  64     // lstm blocks

// tagged path (r10 fallback)
#define SLAB  4096          // bytes per producer slab (1KB data + 3KB pad)
#define BUFB  (NBLK * SLAB) // bytes per h buffer (256 KB)

// sentinel-arena path
#define SLAB2  1024                  // 512 B data + 512 B pad
#define STEPB2 (NBLK * SLAB2)        // 64 KB per step buffer
#define ARENAB ((size_t)SEQ * STEPB2) // 16 MB, write-once

static __device__ __forceinline__ u16 f2bf(float f) {
  unsigned u = __builtin_bit_cast(unsigned, f);
  u += 0x7fffu + ((u >> 16) & 1u);   // RNE
  return (u16)(u >> 16);
}

static __device__ __forceinline__ float fsig(float x) {
  return __builtin_amdgcn_rcpf(1.f + __expf(-x));
}
static __device__ __forceinline__ float ftanh(float x) {
  return 1.f - 2.f * __builtin_amdgcn_rcpf(1.f + __expf(2.f * x));
}

__global__ void cvt_bf16_v4(const float* __restrict__ in, u16* __restrict__ out, long n4) {
  long i = (long)blockIdx.x * blockDim.x + threadIdx.x;
  long stride = (long)gridDim.x * blockDim.x;
  for (; i < n4; i += stride) {
    f4 v = reinterpret_cast<const f4*>(in)[i];
    s4 o;
#pragma unroll
    for (int j = 0; j < 4; ++j) o[j] = (short)f2bf(v[j]);
    reinterpret_cast<s4*>(out)[i] = o;
  }
}

__global__ void embed_gather(const int* __restrict__ x, const float* __restrict__ emb,
                             u16* __restrict__ A) {
  int m = blockIdx.x;                 // m = b*SEQ + t
  long base = (long)x[m] * EMB;
  int e4 = threadIdx.x;               // 0..127, 4 elems each
  f4 v = reinterpret_cast<const f4*>(emb + base)[e4];
  s4 o;
#pragma unroll
  for (int j = 0; j < 4; ++j) o[j] = (short)f2bf(v[j]);
  reinterpret_cast<s4*>(A + (long)m * EMB)[e4] = o;
}

static __device__ __forceinline__ void gload_lds16(const void* g, void* l) {
  __builtin_amdgcn_global_load_lds(
      (const __attribute__((address_space(1))) void*)g,
      (__attribute__((address_space(3))) void*)l, 16, 0, 0);
}

// C = A*B^T + bias, 128x128 tile, BK=64, swizzled staging, bijective XCD
// grid swizzle. TXG=1: out row = t*BATCH + b (time-major xg).  [r10-validated]
template<int TXG>
__global__ __launch_bounds__(256) void gemm_bt(
    const u16* __restrict__ A, const u16* __restrict__ B,
    const float* __restrict__ bias, float* __restrict__ C,
    int M, int N, int K)
{
  __shared__ u16 As[128 * 64];
  __shared__ u16 Bs[128 * 64];
  int tid  = threadIdx.x;
  int lane = tid & 63;
  int wid  = tid >> 6;

  int nwg = gridDim.x * gridDim.y;
  int id  = blockIdx.y * gridDim.x + blockIdx.x;
  int id2 = (id & 7) * (nwg >> 3) + (id >> 3);
  int bx  = id2 % gridDim.x, by = id2 / gridDim.x;
  int m0 = by * 128, n0 = bx * 128;

  int wm = (wid >> 1) * 64, wn = (wid & 1) * 64;
  int r  = lane & 15;
  int hi = lane >> 4;
  f32x4 acc[4][4] = {};

  const u16* gaj[4];
  const u16* gbj[4];
  u16* laj[4];
  u16* lbj[4];
#pragma unroll
  for (int j = 0; j < 4; ++j) {
    int c   = wid * 256 + j * 64 + lane;
    int row = c >> 3;
    int gl  = (c & 7) ^ (row & 7);
    gaj[j] = A + (long)(m0 + row) * K + gl * 8;
    gbj[j] = B + (long)(n0 + row) * K + gl * 8;
    laj[j] = As + wid * 2048 + j * 512;
    lbj[j] = Bs + wid * 2048 + j * 512;
  }

  for (int kt = 0; kt < K; kt += 64) {
    __syncthreads();
#pragma unroll
    for (int j = 0; j < 4; ++j) {
      gload_lds16(gaj[j] + kt, laj[j]);
      gload_lds16(gbj[j] + kt, lbj[j]);
    }
    __syncthreads();
    short8 af[2][4], bf[2][4];
#pragma unroll
    for (int ks = 0; ks < 2; ++ks)
#pragma unroll
      for (int i = 0; i < 4; ++i) {
        int ra = wm + i * 16 + r;
        int rb = wn + i * 16 + r;
        af[ks][i] = *reinterpret_cast<const short8*>(
            &As[ra * 64 + ((ks * 4 + hi) ^ (ra & 7)) * 8]);
        bf[ks][i] = *reinterpret_cast<const short8*>(
            &Bs[rb * 64 + ((ks * 4 + hi) ^ (rb & 7)) * 8]);
      }
#pragma unroll
    for (int ks = 0; ks < 2; ++ks)
#pragma unroll
      for (int i = 0; i < 4; ++i)
#pragma unroll
        for (int j = 0; j < 4; ++j)
          acc[i][j] = __builtin_amdgcn_mfma_f32_16x16x32_bf16(
              af[ks][i], bf[ks][j], acc[i][j], 0, 0, 0);
  }

#pragma unroll
  for (int i = 0; i < 4; ++i) {
    int m = m0 + wm + i * 16 + (hi << 2);
#pragma unroll
    for (int j = 0; j < 4; ++j) {
      int n = n0 + wn + j * 16 + r;
      float bv = bias[n];
#pragma unroll
      for (int jj = 0; jj < 4; ++jj) {
        int mm = m + jj;
        long row;
        if constexpr (TXG) {
          row = (long)(mm & (SEQ - 1)) * BATCH + (mm >> 8);  // t*B + b
        } else {
          row = mm;
        }
        C[row * N + n] = acc[i][j][jj] + bv;
      }
    }
  }
}

// ============ LSTM variant A: sentinel-arena (tagless, half the coherent
// requests of the tagged path). Write-once per-step buffers (no WAR, no
// double-buffer); arena memset 0xFF per launch; a 16B load is valid iff no
// u16 is 0xFFFF (f2bf of |h|<1 can't emit it) — fail-closed retry.
__global__ __launch_bounds__(256, 1) void lstm_arena(
    const float* __restrict__ xg, const u16* __restrict__ Whh,
    const float* __restrict__ b_hh, char* __restrict__ hsb,
    u16* __restrict__ h_all)
{
  __shared__ float part[4][4][16][17];
  __shared__ u16 htile[16][16];

  int tid = threadIdx.x;
  int w = tid >> 6, lane = tid & 63;
  int bid = blockIdx.x;
  int col0 = bid * 16;
  int r  = lane & 15;
  int ko = (lane >> 4) << 3;          // 0,8,16,24

  short8 Wf[8][4];
#pragma unroll
  for (int kk8 = 0; kk8 < 8; ++kk8)
#pragma unroll
    for (int g = 0; g < 4; ++g)
      Wf[kk8][g] = *reinterpret_cast<const short8*>(
          Whh + (long)(g * HID + col0 + r) * HID + (w * 256 + kk8 * 32 + ko));

  // consumer chunk offsets: k = w*256 + (ph*4+kk)*32 + ko
  // producer p = k>>4; in-slab byte = r*32 + (k&15)*2
  unsigned coff[2][4];
#pragma unroll
  for (int ph = 0; ph < 2; ++ph)
#pragma unroll
    for (int kk = 0; kk < 4; ++kk) {
      int p = w * 16 + (ph * 4 + kk) * 2 + (ko >> 4);
      coff[ph][kk] = (unsigned)(p * SLAB2 + r * 32 + (ko & 15) * 2);
    }

  int eb = tid >> 4, ec = tid & 15;
  const float* xgp = xg + (long)eb * GDIM + col0 + ec;
  float bias4[4];
#pragma unroll
  for (int g = 0; g < 4; ++g) bias4[g] = b_hh[g * HID + col0 + ec];
  u16* hap = h_all + (long)eb * SEQ * HID + col0 + ec;
  float creg = 0.f;

  // publish h(0)=0 into step-0 buffer (32 x 16B zero stores)
  if (tid < 32) {
    short8 z = {};
    void* dst = hsb + (size_t)bid * SLAB2 + tid * 16;
    asm volatile("global_store_dwordx4 %0, %1, off sc1" :: "v"(dst), "v"(z) : "memory");
  }

  float xv[4];
#pragma unroll
  for (int g = 0; g < 4; ++g) xv[g] = xgp[g * HID];

  for (int t = 0; t < SEQ; ++t) {
    const char* hb = hsb + (size_t)t * STEPB2;

    f32x4 a0 = {}, a1 = {}, a2 = {}, a3 = {};
#pragma unroll
    for (int ph = 0; ph < 2; ++ph) {
      u32x4 q[4];
      for (;;) {
#pragma unroll
        for (int kk = 0; kk < 4; ++kk)
          asm volatile("global_load_dwordx4 %0, %1, off sc1"
                       : "=v"(q[kk]) : "v"(hb + coff[ph][kk]));
        asm volatile("s_waitcnt vmcnt(0)" ::: "memory");
        __builtin_amdgcn_sched_barrier(0);
        bool ok = true;
#pragma unroll
        for (int kk = 0; kk < 4; ++kk)
#pragma unroll
          for (int j = 0; j < 4; ++j) {
            unsigned v = q[kk][j];
            ok = ok && ((v & 0xffffu) != 0xffffu) && ((v >> 16) != 0xffffu);
          }
        if (__all(ok)) break;
        __builtin_amdgcn_s_sleep(1);
      }
#pragma unroll
      for (int kk = 0; kk < 4; ++kk) {
        short8 av = __builtin_bit_cast(short8, q[kk]);
        a0 = __builtin_amdgcn_mfma_f32_16x16x32_bf16(av, Wf[ph * 4 + kk][0], a0, 0, 0, 0);
        a1 = __builtin_amdgcn_mfma_f32_16x16x32_bf16(av, Wf[ph * 4 + kk][1], a1, 0, 0, 0);
        a2 = __builtin_amdgcn_mfma_f32_16x16x32_bf16(av, Wf[ph * 4 + kk][2], a2, 0, 0, 0);
        a3 = __builtin_amdgcn_mfma_f32_16x16x32_bf16(av, Wf[ph * 4 + kk][3], a3, 0, 0, 0);
      }
    }

#pragma unroll
    for (int j = 0; j < 4; ++j) {
      int batch = ((lane >> 4) << 2) + j;
      part[w][0][batch][r] = a0[j];
      part[w][1][batch][r] = a1[j];
      part[w][2][batch][r] = a2[j];
      part[w][3][batch][r] = a3[j];
    }
    __syncthreads();                       // (A) partials + h(t) reads done

    float pre[4];
#pragma unroll
    for (int g = 0; g < 4; ++g)
      pre[g] = part[0][g][eb][ec] + part[1][g][eb][ec] +
               part[2][g][eb][ec] + part[3][g][eb][ec] + xv[g] + bias4[g];
    float i_ = fsig(pre[0]);
    float f_ = fsig(pre[1]);
    float g_ = ftanh(pre[2]);
    float o_ = fsig(pre[3]);
    float cn = f_ * creg + i_ * g_;
    creg = cn;
    u16 hbf = f2bf(o_ * ftanh(cn));
    htile[eb][ec] = hbf;
    __syncthreads();                       // (B) htile complete

    if (t + 1 < SEQ && tid < 32) {         // publish h(t+1), fire-and-forget
      short8 v = *reinterpret_cast<const short8*>(
          reinterpret_cast<const u16*>(htile) + tid * 8);
      void* dst = hsb + (size_t)(t + 1) * STEPB2 + (size_t)bid * SLAB2 + tid * 16;
      asm volatile("global_store_dwordx4 %0, %1, off sc1" :: "v"(dst), "v"(v) : "memory");
    }

    hap[(long)t * HID] = hbf;
    int tn = (t + 1 < SEQ) ? t + 1 : t;
#pragma unroll
    for (int g = 0; g < 4; ++g)
      xv[g] = xgp[(long)tn * BATCH * GDIM + g * HID];
    // no end barrier: write-once buffers, htile WAR ordered by sync(A)@t+1
  }
}

// ============ LSTM variant B: r10 tagged (proven fallback, 710 us) =======
__global__ __launch_bounds__(256, 1) void lstm_persist(
    const float* __restrict__ xg, const u16* __restrict__ Whh,
    const float* __restrict__ b_hh, unsigned* __restrict__ h_buf,
    u16* __restrict__ h_all)
{
  __shared__ float part[4][4][16][17];

  int tid = threadIdx.x;
  int w = tid >> 6, lane = tid & 63;
  int bid = blockIdx.x;
  int col0 = bid * 16;
  int r  = lane & 15;
  int ko = (lane >> 4) << 3;

  short8 Wf[8][4];
#pragma unroll
  for (int kk8 = 0; kk8 < 8; ++kk8)
#pragma unroll
    for (int g = 0; g < 4; ++g)
      Wf[kk8][g] = *reinterpret_cast<const short8*>(
          Whh + (long)(g * HID + col0 + r) * HID + (w * 256 + kk8 * 32 + ko));

  unsigned soff[2][4];
#pragma unroll
  for (int ph = 0; ph < 2; ++ph)
#pragma unroll
    for (int kk = 0; kk < 4; ++kk) {
      int p = w * 16 + ph * 8 + kk * 2 + (ko >> 4);
      soff[ph][kk] = (unsigned)(p * SLAB + r * 64 + (ko & 8) * 4);
    }
  const char* hbase = reinterpret_cast<const char*>(h_buf);

  int eb = tid >> 4, ec = tid & 15;
  const float* xgp = xg + (long)eb * GDIM + col0 + ec;
  float bias4[4];
#pragma unroll
  for (int g = 0; g < 4; ++g) bias4[g] = b_hh[g * HID + col0 + ec];
  u16* hap = h_all + (long)eb * SEQ * HID + col0 + ec;
  float creg = 0.f;

  __hip_atomic_store(&h_buf[(bid * SLAB / 4) + tid], 1u << 16,
                     __ATOMIC_RELAXED, __HIP_MEMORY_SCOPE_AGENT);

  float xv[4];
#pragma unroll
  for (int g = 0; g < 4; ++g) xv[g] = xgp[g * HID];

  for (int t = 0; t < SEQ; ++t) {
    unsigned want = (unsigned)(t + 1);
    const char* hb = hbase + ((t & 1) ? BUFB : 0);

    f32x4 a0 = {}, a1 = {}, a2 = {}, a3 = {};
#pragma unroll
    for (int ph = 0; ph < 2; ++ph) {
      u32x4 q[4][2];
      for (;;) {
#pragma unroll
        for (int kk = 0; kk < 4; ++kk) {
          const void* a = hb + soff[ph][kk];
          const void* b = hb + soff[ph][kk] + 16;
          asm volatile("global_load_dwordx4 %0, %1, off sc1"
                       : "=v"(q[kk][0]) : "v"(a));
          asm volatile("global_load_dwordx4 %0, %1, off sc1"
                       : "=v"(q[kk][1]) : "v"(b));
        }
        asm volatile("s_waitcnt vmcnt(0)" ::: "memory");
        __builtin_amdgcn_sched_barrier(0);
        bool allok = true;
#pragma unroll
        for (int kk = 0; kk < 4; ++kk)
#pragma unroll
          for (int v = 0; v < 2; ++v)
#pragma unroll
            for (int j = 0; j < 4; ++j)
              allok = allok && ((q[kk][v][j] >> 16) >= want);
        if (__all(allok)) break;
        __builtin_amdgcn_s_sleep(1);
      }
#pragma unroll
      for (int kk = 0; kk < 4; ++kk) {
        u32x4 wv;
        wv[0] = (q[kk][0][0] & 0xffffu) | (q[kk][0][1] << 16);
        wv[1] = (q[kk][0][2] & 0xffffu) | (q[kk][0][3] << 16);
        wv[2] = (q[kk][1][0] & 0xffffu) | (q[kk][1][1] << 16);
        wv[3] = (q[kk][1][2] & 0xffffu) | (q[kk][1][3] << 16);
        short8 av = __builtin_bit_cast(short8, wv);
        a0 = __builtin_amdgcn_mfma_f32_16x16x32_bf16(av, Wf[ph * 4 + kk][0], a0, 0, 0, 0);
        a1 = __builtin_amdgcn_mfma_f32_16x16x32_bf16(av, Wf[ph * 4 + kk][1], a1, 0, 0, 0);
        a2 = __builtin_amdgcn_mfma_f32_16x16x32_bf16(av, Wf[ph * 4 + kk][2], a2, 0, 0, 0);
        a3 = __builtin_amdgcn_mfma_f32_16x16x32_bf16(av, Wf[ph * 4 + kk][3], a3, 0, 0, 0);
      }
    }

#pragma unroll
    for (int j = 0; j < 4; ++j) {
      int batch = ((lane >> 4) << 2) + j;
      part[w][0][batch][r] = a0[j];
      part[w][1][batch][r] = a1[j];
      part[w][2][batch][r] = a2[j];
      part[w][3][batch][r] = a3[j];
    }
    __syncthreads();

    float pre[4];
#pragma unroll
    for (int g = 0; g < 4; ++g)
      pre[g] = part[0][g][eb][ec] + part[1][g][eb][ec] +
               part[2][g][eb][ec] + part[3][g][eb][ec] + xv[g] + bias4[g];
    float i_ = fsig(pre[0]);
    float f_ = fsig(pre[1]);
    float g_ = ftanh(pre[2]);
    float o_ = fsig(pre[3]);
    float cn = f_ * creg + i_ * g_;
    creg = cn;
    u16 hbf = f2bf(o_ * ftanh(cn));

    if (t + 1 < SEQ) {
      unsigned word = (unsigned)hbf | ((unsigned)(t + 2) << 16);
      __hip_atomic_store(
          &h_buf[(((t + 1) & 1) ? BUFB / 4 : 0) + (bid * SLAB / 4) + tid],
          word, __ATOMIC_RELAXED, __HIP_MEMORY_SCOPE_AGENT);
    }

    hap[(long)t * HID] = hbf;
    int tn = (t + 1 < SEQ) ? t + 1 : t;
#pragma unroll
    for (int g = 0; g < 4; ++g)
      xv[g] = xgp[(long)tn * BATCH * GDIM + g * HID];

    __syncthreads();
  }
}

extern "C" void kernel_launch(void* const* d_in, const int* in_sizes, int n_in,
                              void* d_out, int out_size, void* d_ws, size_t ws_size,
                              hipStream_t stream) {
  const int*   x      = (const int*)d_in[0];
  const float* emb    = (const float*)d_in[1];
  const float* W_ih   = (const float*)d_in[2];
  const float* W_hh   = (const float*)d_in[3];
  const float* b_ih   = (const float*)d_in[4];
  const float* b_hh   = (const float*)d_in[5];
  const float* head_W = (const float*)d_in[6];
  const float* head_b = (const float*)d_in[7];
  float* out = (float*)d_out;

  char* ws = (char*)d_ws;
  size_t off = 0;
  auto alloc = [&](size_t bytes) -> void* {
    void* p = ws + off;
    off += (bytes + 255) & ~(size_t)255;
    return p;
  };
  u16*   Aemb  = (u16*)alloc((size_t)MTOT * EMB * 2);
  u16*   Wih_b = (u16*)alloc((size_t)GDIM * EMB * 2);
  u16*   Whh_b = (u16*)alloc((size_t)GDIM * HID * 2);
  u16*   HW_b  = (u16*)alloc((size_t)VOCAB * HID * 2);
  float* xg    = (float*)alloc((size_t)MTOT * GDIM * 4);   // time-major [T][B][4H]
  u16*   h_all = (u16*)alloc((size_t)MTOT * HID * 2);

  // choose exchange protocol by workspace capacity (r9's failure was the
  // 182.6MB overflow; the check makes the arena safe to attempt)
  size_t off_arena = off;
  bool use_arena = (off_arena + ARENAB + 256 <= ws_size);

  cvt_bf16_v4<<<1024, 256, 0, stream>>>(W_ih, Wih_b, (long)GDIM * EMB / 4);
  cvt_bf16_v4<<<1024, 256, 0, stream>>>(W_hh, Whh_b, (long)GDIM * HID / 4);
  cvt_bf16_v4<<<2048, 256, 0, stream>>>(head_W, HW_b, (long)VOCAB * HID / 4);
  embed_gather<<<MTOT, 128, 0, stream>>>(x, emb, Aemb);

  gemm_bt<1><<<dim3(GDIM / 128, MTOT / 128), 256, 0, stream>>>(
      Aemb, Wih_b, b_ih, xg, MTOT, GDIM, EMB);

  if (use_arena) {
    char* hsb = (char*)alloc(ARENAB);
    hipMemsetAsync(hsb, 0xFF, ARENAB, stream);   // sentinels (also clears
                                                 // stale prior-replay h)
    lstm_arena<<<dim3(NBLK), dim3(256), 0, stream>>>(
        xg, Whh_b, b_hh, hsb, h_all);
  } else {
    unsigned* h_buf = (unsigned*)alloc((size_t)2 * BUFB);
    hipMemsetAsync(h_buf, 0, (size_t)2 * BUFB, stream);   // tags fail closed
    lstm_persist<<<dim3(NBLK), dim3(256), 0, stream>>>(
        xg, Whh_b, b_hh, h_buf, h_all);
  }

  gemm_bt<0><<<dim3(VOCAB / 128, MTOT / 128), 256, 0, stream>>>(
      h_all, HW_b, head_b, out, MTOT, VOCAB, HID);
}